// Round 7
// baseline (1956.711 us; speedup 1.0000x reference)
//
#include <hip/hip_runtime.h>
#include <hip/hip_bf16.h>

#define NH 8
#define NB 8
#define NS 1024
#define NTOK (NB*NS)            // 8192
#define CAPV 15.0f
#define EPSV 1e-6f
#define NPAD_UP 2304            // [W_up_l 1536 | W_up_r 768]
#define SFW2 3904               // [skip 768 | i,f 16 + pad 48 | o 768 | q 768 | k 768 | v 768]
#define OQKV_W 3072
#define INV_SQRT_D 0.10206207261596575f
#define YS_ELEMS ((size_t)NTOK * 768)   // 6291456

typedef __attribute__((ext_vector_type(8))) short short8;
typedef __attribute__((ext_vector_type(4))) float f32x4;
typedef __hip_bfloat16 bf16;

__device__ inline float cvt(float v) { return v; }
__device__ inline float cvt(bf16 v) { return __bfloat162float(v); }

// ---------------- weight cast ----------------
__global__ void cast_pad_kernel(const float* __restrict__ src, bf16* __restrict__ dst, long n) {
  long i = (long)blockIdx.x * 256 + threadIdx.x;
  if (i < n) dst[i] = __float2bfloat16(src[i]);
}

// reordered big weight: rows [0,768) W_skip | [768,784) fused(i,f) | [784,832) 0 | [832,3904) fused(o,q,k,v)
__global__ void build_wsf2_kernel(const float* __restrict__ Wskip, const float* __restrict__ fusedW,
                                  bf16* __restrict__ dst) {
  int k = blockIdx.x * 256 + threadIdx.x;   // 0..1535
  int r = blockIdx.y;                        // 0..3903
  float v;
  if (r < 768) v = Wskip[(size_t)r * 1536 + k];
  else if (r < 784) v = fusedW[(size_t)(r - 768) * 1536 + k];
  else if (r < 832) v = 0.f;
  else v = fusedW[(size_t)(r - 816) * 1536 + k];
  dst[(size_t)r * 1536 + k] = __float2bfloat16(v);
}

__global__ void build_bias2_kernel(const float* __restrict__ fb, float* __restrict__ bias) {
  int i = blockIdx.x * 256 + threadIdx.x;
  if (i >= SFW2) return;
  float v = 0.f;
  if (i >= 768 && i < 784) v = fb[i - 768];
  else if (i >= 832) v = fb[i - 816];
  bias[i] = v;
}

// ---------------- layernorm (768 wide) -> bf16 ----------------
template <typename T>
__global__ __launch_bounds__(256) void ln_kernel(const T* __restrict__ x,
    const float* __restrict__ g, const float* __restrict__ bta, bf16* __restrict__ out) {
  int row = blockIdx.x;
  const T* xr = x + (size_t)row * 768;
  int t = threadIdx.x;
  float v0 = cvt(xr[t]), v1 = cvt(xr[t + 256]), v2 = cvt(xr[t + 512]);
  float ssum = v0 + v1 + v2;
  __shared__ float red[8];
  #pragma unroll
  for (int m = 1; m < 64; m <<= 1) ssum += __shfl_xor(ssum, m);
  int wave = t >> 6, lane = t & 63;
  if (lane == 0) red[wave] = ssum;
  __syncthreads();
  float mu = (red[0] + red[1] + red[2] + red[3]) * (1.0f / 768.0f);
  float d0 = v0 - mu, d1 = v1 - mu, d2 = v2 - mu;
  float sq = d0 * d0 + d1 * d1 + d2 * d2;
  #pragma unroll
  for (int m = 1; m < 64; m <<= 1) sq += __shfl_xor(sq, m);
  if (lane == 0) red[wave + 4] = sq;
  __syncthreads();
  float var = (red[4] + red[5] + red[6] + red[7]) * (1.0f / 768.0f);
  float rs = rsqrtf(var + EPSV);
  size_t o = (size_t)row * 768;
  out[o + t]       = __float2bfloat16(d0 * rs * g[t]       + bta[t]);
  out[o + t + 256] = __float2bfloat16(d1 * rs * g[t + 256] + bta[t + 256]);
  out[o + t + 512] = __float2bfloat16(d2 * rs * g[t + 512] + bta[t + 512]);
}

// ---------------- GEMM core fragment loop ----------------
// wave -> 64x64 tile of C[M,N] = A[M,K]*W[N,K]^T via 4x4 mfma_f32_16x16x32_bf16
#define GEMM_BODY(A, W, K)                                                        \
  int lane = threadIdx.x & 63;                                                    \
  int wave = threadIdx.x >> 6;                                                    \
  int n0 = blockIdx.x * 64;                                                       \
  int m0 = (blockIdx.y * 4 + wave) * 64;                                          \
  int rsel = lane & 15;                                                           \
  int koff = (lane >> 4) * 8;                                                     \
  const bf16* aptr = (A) + (size_t)(m0 + rsel) * (K) + koff;                      \
  const bf16* wptr = (W) + (size_t)(n0 + rsel) * (K) + koff;                      \
  f32x4 acc[4][4];                                                                \
  _Pragma("unroll") for (int i = 0; i < 4; i++)                                   \
    _Pragma("unroll") for (int j = 0; j < 4; j++)                                 \
      acc[i][j] = (f32x4){0.f, 0.f, 0.f, 0.f};                                    \
  for (int k0 = 0; k0 < (K); k0 += 32) {                                          \
    short8 afr[4], wfr[4];                                                        \
    _Pragma("unroll") for (int i = 0; i < 4; i++)                                 \
      afr[i] = *reinterpret_cast<const short8*>(aptr + (size_t)i * 16 * (K) + k0);\
    _Pragma("unroll") for (int j = 0; j < 4; j++)                                 \
      wfr[j] = *reinterpret_cast<const short8*>(wptr + (size_t)j * 16 * (K) + k0);\
    _Pragma("unroll") for (int i = 0; i < 4; i++)                                 \
      _Pragma("unroll") for (int j = 0; j < 4; j++)                               \
        acc[i][j] = __builtin_amdgcn_mfma_f32_16x16x32_bf16(afr[i], wfr[j], acc[i][j], 0, 0, 0); \
  }                                                                               \
  int crow_base = m0 + (lane >> 4) * 4;                                           \
  int ccol_base = n0 + (lane & 15);

// gemm1: up-projection -> bf16
__global__ __launch_bounds__(256) void gemm_up_kernel(const bf16* __restrict__ A,
    const bf16* __restrict__ W, bf16* __restrict__ C, int N, int K) {
  GEMM_BODY(A, W, K)
  #pragma unroll
  for (int i = 0; i < 4; i++)
    #pragma unroll
    for (int j = 0; j < 4; j++) {
      int col = ccol_base + j * 16;
      #pragma unroll
      for (int r = 0; r < 4; r++)
        C[(size_t)(crow_base + i * 16 + r) * N + col] = __float2bfloat16(acc[i][j][r]);
    }
}

// gemm2: fused/skip projection with segment-routed epilogue
__global__ __launch_bounds__(256) void gemm_sf_kernel(const bf16* __restrict__ A,
    const bf16* __restrict__ W, const float* __restrict__ bias,
    bf16* __restrict__ skipb, float* __restrict__ gates, bf16* __restrict__ oqkv) {
  const int K = 1536;
  GEMM_BODY(A, W, K)
  #pragma unroll
  for (int i = 0; i < 4; i++)
    #pragma unroll
    for (int j = 0; j < 4; j++) {
      int col = ccol_base + j * 16;
      float bv = bias[col];
      #pragma unroll
      for (int r = 0; r < 4; r++) {
        int row = crow_base + i * 16 + r;
        float v = acc[i][j][r] + bv;
        if (col < 768)       skipb[(size_t)row * 768 + col] = __float2bfloat16(v);
        else if (col < 832)  gates[(size_t)row * 64 + (col - 768)] = v;
        else                 oqkv[(size_t)row * OQKV_W + (col - 832)] = __float2bfloat16(v);
      }
    }
}

// gemm3: down-projection with fused final epilogue -> ys (f32, d_out)
__global__ __launch_bounds__(256) void gemm_down_kernel(const bf16* __restrict__ A,
    const bf16* __restrict__ W, const bf16* __restrict__ skipb, const bf16* __restrict__ srt,
    const float* __restrict__ x, float* __restrict__ ys) {
  const int K = 768;
  GEMM_BODY(A, W, K)
  #pragma unroll
  for (int i = 0; i < 4; i++)
    #pragma unroll
    for (int j = 0; j < 4; j++) {
      int col = ccol_base + j * 16;
      #pragma unroll
      for (int r = 0; r < 4; r++) {
        size_t idx = (size_t)(crow_base + i * 16 + r) * 768 + col;
        ys[idx] = (acc[i][j][r] + cvt(skipb[idx])) * cvt(srt[idx]) + x[idx];
      }
    }
}

// ---------------- causal feature conv + silu; silu(rt) ----------------
__global__ __launch_bounds__(256) void conv_silu_kernel(const bf16* __restrict__ up,
    const float* __restrict__ cw, bf16* __restrict__ xc, bf16* __restrict__ srt) {
  int row = blockIdx.x;
  const bf16* xr = up + (size_t)row * NPAD_UP;
  float w0 = cw[0], w1 = cw[1], w2 = cw[2], w3 = cw[3];
  int t = threadIdx.x;
  #pragma unroll
  for (int u = 0; u < 6; ++u) {
    int j = t + u * 256;
    float xm3 = j >= 3 ? cvt(xr[j - 3]) : 0.f;
    float xm2 = j >= 2 ? cvt(xr[j - 2]) : 0.f;
    float xm1 = j >= 1 ? cvt(xr[j - 1]) : 0.f;
    float x0  = cvt(xr[j]);
    float c = w0 * xm3 + w1 * xm2 + w2 * xm1 + w3 * x0;
    xc[(size_t)row * 1536 + j] = __float2bfloat16(c / (1.f + expf(-c)));
  }
  #pragma unroll
  for (int u = 0; u < 3; ++u) {
    int j = t + u * 256;
    float r = cvt(xr[1536 + j]);
    srt[(size_t)row * 768 + j] = __float2bfloat16(r / (1.f + expf(-r)));
  }
}

// ---------------- sequential mLSTM scan: one block per (b,h) ----------------
__global__ __launch_bounds__(256) void scan_kernel(const float* __restrict__ gates,
    const bf16* __restrict__ oqkv, bf16* __restrict__ hbuf, float* __restrict__ st) {
  int bh = blockIdx.x;
  int b = bh >> 3, hd = bh & 7;
  int t = threadIdx.x;
  int dg = t >> 4, eg = t & 15;
  int d0 = dg * 6, e0 = eg * 6;
  float c[6][6];
  float nv[6];
  #pragma unroll
  for (int i = 0; i < 6; i++) {
    nv[i] = 1.0f;
    #pragma unroll
    for (int j = 0; j < 6; j++) c[i][j] = 0.f;
  }
  float mcur = 0.f;
  __shared__ float qs[96], ks[96], vs[96], os[96];
  const bf16* obase = oqkv + (size_t)b * NS * OQKV_W;
  const float* gbase = gates + (size_t)b * NS * 64;
  int ocol = hd * 96, qcol = 768 + hd * 96, kcol = 1536 + hd * 96, vcol = 2304 + hd * 96;
  float rq = 0.f, rk = 0.f, rv = 0.f, ro = 0.f;
  float gi, gf;
  {
    if (t < 96) {
      rq = cvt(obase[qcol + t]); rk = cvt(obase[kcol + t]);
      rv = cvt(obase[vcol + t]); ro = cvt(obase[ocol + t]);
    }
    gi = gbase[hd]; gf = gbase[8 + hd];
  }
  for (int s = 0; s < NS; ++s) {
    __syncthreads();
    if (t < 96) {
      qs[t] = rq;
      ks[t] = rk * INV_SQRT_D;
      vs[t] = rv;
      float oc = CAPV * tanhf(ro * (1.0f / CAPV));
      os[t] = 1.f / (1.f + expf(-oc));
    }
    float gic = gi, gfc = gf;
    __syncthreads();
    if (s + 1 < NS) {
      const bf16* rn = obase + (size_t)(s + 1) * OQKV_W;
      if (t < 96) {
        rq = cvt(rn[qcol + t]); rk = cvt(rn[kcol + t]);
        rv = cvt(rn[vcol + t]); ro = cvt(rn[ocol + t]);
      }
      const float* gn = gbase + (size_t)(s + 1) * 64;
      gi = gn[hd]; gf = gn[8 + hd];
    }
    float icap = CAPV * tanhf(gic * (1.0f / CAPV));
    float fcap = CAPV * tanhf(gfc * (1.0f / CAPV));
    float mnew = fmaxf(fcap + mcur, icap);
    float ie = expf(icap - mnew);
    float fe = expf(fcap - mnew + mcur);
    mcur = mnew;
    float qv[6], kv[6];
    #pragma unroll
    for (int j = 0; j < 6; j++) { qv[j] = qs[e0 + j]; kv[j] = ks[e0 + j]; }
    float den = 0.f;
    #pragma unroll
    for (int j = 0; j < 6; j++) { nv[j] = fe * nv[j] + ie * kv[j]; den += nv[j] * qv[j]; }
    float num[6];
    #pragma unroll
    for (int i = 0; i < 6; i++) {
      float iv = ie * vs[d0 + i];
      float a = 0.f;
      #pragma unroll
      for (int j = 0; j < 6; j++) {
        c[i][j] = fe * c[i][j] + iv * kv[j];
        a += c[i][j] * qv[j];
      }
      num[i] = a;
    }
    #pragma unroll
    for (int m = 1; m < 16; m <<= 1) {
      #pragma unroll
      for (int i = 0; i < 6; i++) num[i] += __shfl_xor(num[i], m);
      den += __shfl_xor(den, m);
    }
    den = fmaxf(den, 1.0f);
    float rden = 1.0f / den;
    if (eg < 6) {
      float hv = 0.f;
      #pragma unroll
      for (int i = 0; i < 6; i++) if (eg == i) hv = num[i];
      int colr = d0 + eg;
      hbuf[((size_t)(b * NS + s)) * 768 + hd * 96 + colr] = __float2bfloat16(os[colr] * hv * rden);
    }
  }
  // final states (f32) at d_out tail: C [64,96,96] | n [64,96] | m [64]
  float* Cst = st;
  float* nst = st + (size_t)64 * 96 * 96;
  float* mst = nst + 64 * 96;
  size_t cb = (size_t)bh * 96 * 96;
  #pragma unroll
  for (int i = 0; i < 6; i++)
    #pragma unroll
    for (int j = 0; j < 6; j++)
      Cst[cb + (size_t)(d0 + i) * 96 + e0 + j] = c[i][j];
  if (dg == 0) {
    #pragma unroll
    for (int j = 0; j < 6; j++) nst[(size_t)bh * 96 + e0 + j] = nv[j];
  }
  if (t == 0) mst[bh] = mcur;
}

extern "C" void kernel_launch(void* const* d_in, const int* in_sizes, int n_in,
                              void* d_out, int out_size, void* d_ws, size_t ws_size,
                              hipStream_t stream) {
  const float* x       = (const float*)d_in[0];
  const float* ln1_g   = (const float*)d_in[1];
  const float* ln1_b   = (const float*)d_in[2];
  const float* W_up_l  = (const float*)d_in[3];
  const float* W_up_r  = (const float*)d_in[4];
  const float* conv_w  = (const float*)d_in[5];
  const float* W_skip  = (const float*)d_in[6];
  const float* fused_W = (const float*)d_in[7];
  const float* fused_b = (const float*)d_in[8];
  const float* ln2_g   = (const float*)d_in[9];
  const float* ln2_b   = (const float*)d_in[10];
  const float* W_down  = (const float*)d_in[11];

  char* ws = (char*)d_ws;
  size_t off = 0;
  auto carve = [&](size_t bytes) -> char* {
    char* p = ws + off;
    off += (bytes + 255) & ~(size_t)255;
    return p;
  };
  bf16* wup    = (bf16*)carve((size_t)NPAD_UP * 768 * 2);   // 3.5 MB
  bf16* wsf2   = (bf16*)carve((size_t)SFW2 * 1536 * 2);     // 12.0 MB
  bf16* wdn    = (bf16*)carve((size_t)768 * 768 * 2);       // 1.2 MB
  float* bias2 = (float*)carve(SFW2 * 4);
  bf16* srt    = (bf16*)carve((size_t)NTOK * 768 * 2);      // 12.6 MB
  bf16* skipb  = (bf16*)carve((size_t)NTOK * 768 * 2);      // 12.6 MB
  float* gates = (float*)carve((size_t)NTOK * 64 * 4);      // 2.1 MB
  bf16* oqkv   = (bf16*)carve((size_t)NTOK * OQKV_W * 2);   // 50.3 MB
  bf16* xc     = (bf16*)carve((size_t)NTOK * 1536 * 2);     // 25.2 MB
  // aliased region: phase A {xn, up_out} then phase B/C {hbuf, hn}
  char* R      = carve((size_t)NTOK * 768 * 2 + (size_t)NTOK * NPAD_UP * 2);  // 50.3 MB
  bf16* xn     = (bf16*)R;
  bf16* up_out = (bf16*)(R + (size_t)NTOK * 768 * 2);
  bf16* hbuf   = (bf16*)R;
  bf16* hn     = (bf16*)(R + (size_t)NTOK * 768 * 2);
  // total ~170 MB (round-3 footprint, known to run)

  auto blocks = [](long n) { return (unsigned)((n + 255) / 256); };

  // weights -> bf16
  long n1 = 1536L * 768, n2 = 768L * 768;
  cast_pad_kernel<<<blocks(n1), 256, 0, stream>>>(W_up_l, wup, n1);
  cast_pad_kernel<<<blocks(n2), 256, 0, stream>>>(W_up_r, wup + n1, n2);
  build_wsf2_kernel<<<dim3(6, SFW2), 256, 0, stream>>>(W_skip, fused_W, wsf2);
  cast_pad_kernel<<<blocks(n2), 256, 0, stream>>>(W_down, wdn, n2);
  build_bias2_kernel<<<blocks(SFW2), 256, 0, stream>>>(fused_b, bias2);

  float* out_f = (float*)d_out;

  // phase A
  ln_kernel<float><<<NTOK, 256, 0, stream>>>(x, ln1_g, ln1_b, xn);
  gemm_up_kernel<<<dim3(NPAD_UP / 64, NTOK / 256), 256, 0, stream>>>(
      xn, wup, up_out, NPAD_UP, 768);
  conv_silu_kernel<<<NTOK, 256, 0, stream>>>(up_out, conv_w, xc, srt);
  gemm_sf_kernel<<<dim3(SFW2 / 64, NTOK / 256), 256, 0, stream>>>(
      xc, wsf2, bias2, skipb, gates, oqkv);

  // phase B: recurrent scan (64 blocks), f32 states -> d_out tail
  scan_kernel<<<64, 256, 0, stream>>>(gates, oqkv, hbuf, out_f + YS_ELEMS);

  // phase C
  ln_kernel<bf16><<<NTOK, 256, 0, stream>>>(hbuf, ln2_g, ln2_b, hn);
  gemm_down_kernel<<<dim3(768 / 64, NTOK / 256), 256, 0, stream>>>(
      hn, wdn, skipb, srt, x, out_f);
}

// Round 8
// 780.805 us; speedup vs baseline: 2.5060x; 2.5060x over previous
//
#include <hip/hip_runtime.h>
#include <hip/hip_bf16.h>

#define NH 8
#define NB 8
#define NS 1024
#define NTOK (NB*NS)            // 8192
#define CAPV 15.0f
#define EPSV 1e-6f
#define NPAD_UP 2304            // [W_up_l 1536 | W_up_r 768]
#define SFW2 3904               // [skip 768 | i,f 16 + pad 48 | o 768 | q 768 | k 768 | v 768]
#define OQKV_W 3072
#define INV_SQRT_D 0.10206207261596575f
#define YS_ELEMS ((size_t)NTOK * 768)   // 6291456
#define CH 64                   // chunk length
#define NCH 16                  // chunks per (b,h)

typedef __attribute__((ext_vector_type(8))) short short8;
typedef __attribute__((ext_vector_type(4))) float f32x4;
typedef __hip_bfloat16 bf16;

__device__ inline float cvt(float v) { return v; }
__device__ inline float cvt(bf16 v) { return __bfloat162float(v); }

// ---------------- weight cast ----------------
__global__ void cast_pad_kernel(const float* __restrict__ src, bf16* __restrict__ dst, long n) {
  long i = (long)blockIdx.x * 256 + threadIdx.x;
  if (i < n) dst[i] = __float2bfloat16(src[i]);
}

// rows [0,768) W_skip | [768,784) fused(i,f) | [784,832) 0 | [832,3904) fused(o,q,k,v)
__global__ void build_wsf2_kernel(const float* __restrict__ Wskip, const float* __restrict__ fusedW,
                                  bf16* __restrict__ dst) {
  int k = blockIdx.x * 256 + threadIdx.x;   // 0..1535
  int r = blockIdx.y;                        // 0..3903
  float v;
  if (r < 768) v = Wskip[(size_t)r * 1536 + k];
  else if (r < 784) v = fusedW[(size_t)(r - 768) * 1536 + k];
  else if (r < 832) v = 0.f;
  else v = fusedW[(size_t)(r - 816) * 1536 + k];
  dst[(size_t)r * 1536 + k] = __float2bfloat16(v);
}

__global__ void build_bias2_kernel(const float* __restrict__ fb, float* __restrict__ bias) {
  int i = blockIdx.x * 256 + threadIdx.x;
  if (i >= SFW2) return;
  float v = 0.f;
  if (i >= 768 && i < 784) v = fb[i - 768];
  else if (i >= 832) v = fb[i - 816];
  bias[i] = v;
}

// ---------------- layernorm (768 wide) -> bf16 ----------------
template <typename T>
__global__ __launch_bounds__(256) void ln_kernel(const T* __restrict__ x,
    const float* __restrict__ g, const float* __restrict__ bta, bf16* __restrict__ out) {
  int row = blockIdx.x;
  const T* xr = x + (size_t)row * 768;
  int t = threadIdx.x;
  float v0 = cvt(xr[t]), v1 = cvt(xr[t + 256]), v2 = cvt(xr[t + 512]);
  float ssum = v0 + v1 + v2;
  __shared__ float red[8];
  #pragma unroll
  for (int m = 1; m < 64; m <<= 1) ssum += __shfl_xor(ssum, m);
  int wave = t >> 6, lane = t & 63;
  if (lane == 0) red[wave] = ssum;
  __syncthreads();
  float mu = (red[0] + red[1] + red[2] + red[3]) * (1.0f / 768.0f);
  float d0 = v0 - mu, d1 = v1 - mu, d2 = v2 - mu;
  float sq = d0 * d0 + d1 * d1 + d2 * d2;
  #pragma unroll
  for (int m = 1; m < 64; m <<= 1) sq += __shfl_xor(sq, m);
  if (lane == 0) red[wave + 4] = sq;
  __syncthreads();
  float var = (red[4] + red[5] + red[6] + red[7]) * (1.0f / 768.0f);
  float rs = rsqrtf(var + EPSV);
  size_t o = (size_t)row * 768;
  out[o + t]       = __float2bfloat16(d0 * rs * g[t]       + bta[t]);
  out[o + t + 256] = __float2bfloat16(d1 * rs * g[t + 256] + bta[t + 256]);
  out[o + t + 512] = __float2bfloat16(d2 * rs * g[t + 512] + bta[t + 512]);
}

// ---------------- GEMM core fragment loop ----------------
#define GEMM_BODY(A, W, K)                                                        \
  int lane = threadIdx.x & 63;                                                    \
  int wave = threadIdx.x >> 6;                                                    \
  int n0 = blockIdx.x * 64;                                                       \
  int m0 = (blockIdx.y * 4 + wave) * 64;                                          \
  int rsel = lane & 15;                                                           \
  int koff = (lane >> 4) * 8;                                                     \
  const bf16* aptr = (A) + (size_t)(m0 + rsel) * (K) + koff;                      \
  const bf16* wptr = (W) + (size_t)(n0 + rsel) * (K) + koff;                      \
  f32x4 acc[4][4];                                                                \
  _Pragma("unroll") for (int i = 0; i < 4; i++)                                   \
    _Pragma("unroll") for (int j = 0; j < 4; j++)                                 \
      acc[i][j] = (f32x4){0.f, 0.f, 0.f, 0.f};                                    \
  for (int k0 = 0; k0 < (K); k0 += 32) {                                          \
    short8 afr[4], wfr[4];                                                        \
    _Pragma("unroll") for (int i = 0; i < 4; i++)                                 \
      afr[i] = *reinterpret_cast<const short8*>(aptr + (size_t)i * 16 * (K) + k0);\
    _Pragma("unroll") for (int j = 0; j < 4; j++)                                 \
      wfr[j] = *reinterpret_cast<const short8*>(wptr + (size_t)j * 16 * (K) + k0);\
    _Pragma("unroll") for (int i = 0; i < 4; i++)                                 \
      _Pragma("unroll") for (int j = 0; j < 4; j++)                               \
        acc[i][j] = __builtin_amdgcn_mfma_f32_16x16x32_bf16(afr[i], wfr[j], acc[i][j], 0, 0, 0); \
  }                                                                               \
  int crow_base = m0 + (lane >> 4) * 4;                                           \
  int ccol_base = n0 + (lane & 15);

__global__ __launch_bounds__(256) void gemm_up_kernel(const bf16* __restrict__ A,
    const bf16* __restrict__ W, bf16* __restrict__ C, int N, int K) {
  GEMM_BODY(A, W, K)
  #pragma unroll
  for (int i = 0; i < 4; i++)
    #pragma unroll
    for (int j = 0; j < 4; j++) {
      int col = ccol_base + j * 16;
      #pragma unroll
      for (int r = 0; r < 4; r++)
        C[(size_t)(crow_base + i * 16 + r) * N + col] = __float2bfloat16(acc[i][j][r]);
    }
}

__global__ __launch_bounds__(256) void gemm_sf_kernel(const bf16* __restrict__ A,
    const bf16* __restrict__ W, const float* __restrict__ bias,
    bf16* __restrict__ skipb, float* __restrict__ gates, bf16* __restrict__ oqkv) {
  const int K = 1536;
  GEMM_BODY(A, W, K)
  #pragma unroll
  for (int i = 0; i < 4; i++)
    #pragma unroll
    for (int j = 0; j < 4; j++) {
      int col = ccol_base + j * 16;
      float bv = bias[col];
      #pragma unroll
      for (int r = 0; r < 4; r++) {
        int row = crow_base + i * 16 + r;
        float v = acc[i][j][r] + bv;
        if (col < 768)       skipb[(size_t)row * 768 + col] = __float2bfloat16(v);
        else if (col < 832)  gates[(size_t)row * 64 + (col - 768)] = v;
        else                 oqkv[(size_t)row * OQKV_W + (col - 832)] = __float2bfloat16(v);
      }
    }
}

__global__ __launch_bounds__(256) void gemm_down_kernel(const bf16* __restrict__ A,
    const bf16* __restrict__ W, const bf16* __restrict__ skipb, const bf16* __restrict__ srt,
    const float* __restrict__ x, float* __restrict__ ys) {
  const int K = 768;
  GEMM_BODY(A, W, K)
  #pragma unroll
  for (int i = 0; i < 4; i++)
    #pragma unroll
    for (int j = 0; j < 4; j++) {
      int col = ccol_base + j * 16;
      #pragma unroll
      for (int r = 0; r < 4; r++) {
        size_t idx = (size_t)(crow_base + i * 16 + r) * 768 + col;
        ys[idx] = (acc[i][j][r] + cvt(skipb[idx])) * cvt(srt[idx]) + x[idx];
      }
    }
}

// ---------------- causal feature conv + silu; silu(rt) ----------------
__global__ __launch_bounds__(256) void conv_silu_kernel(const bf16* __restrict__ up,
    const float* __restrict__ cw, bf16* __restrict__ xc, bf16* __restrict__ srt) {
  int row = blockIdx.x;
  const bf16* xr = up + (size_t)row * NPAD_UP;
  float w0 = cw[0], w1 = cw[1], w2 = cw[2], w3 = cw[3];
  int t = threadIdx.x;
  #pragma unroll
  for (int u = 0; u < 6; ++u) {
    int j = t + u * 256;
    float xm3 = j >= 3 ? cvt(xr[j - 3]) : 0.f;
    float xm2 = j >= 2 ? cvt(xr[j - 2]) : 0.f;
    float xm1 = j >= 1 ? cvt(xr[j - 1]) : 0.f;
    float x0  = cvt(xr[j]);
    float c = w0 * xm3 + w1 * xm2 + w2 * xm1 + w3 * x0;
    xc[(size_t)row * 1536 + j] = __float2bfloat16(c / (1.f + expf(-c)));
  }
  #pragma unroll
  for (int u = 0; u < 3; ++u) {
    int j = t + u * 256;
    float r = cvt(xr[1536 + j]);
    srt[(size_t)row * 768 + j] = __float2bfloat16(r / (1.f + expf(-r)));
  }
}

// ---------------- B0a: cap gates, transpose to [bh][t] ----------------
__global__ __launch_bounds__(256) void gate_cap_kernel(const float* __restrict__ gates,
    float* __restrict__ icapT, float* __restrict__ fcapT) {
  int idx = blockIdx.x * 256 + threadIdx.x;   // 0..65535
  int bh = idx >> 10, t = idx & 1023;
  int b = bh >> 3, h = bh & 7;
  size_t row = (size_t)(b * 1024 + t) * 64;
  icapT[idx] = CAPV * tanhf(gates[row + h] * (1.f / CAPV));
  fcapT[idx] = CAPV * tanhf(gates[row + 8 + h] * (1.f / CAPV));
}

// ---------------- B0b: sequential m-scan + per-chunk A cumsum (lane = bh) ----------------
__global__ __launch_bounds__(64) void mscan_kernel(const float* __restrict__ icapT,
    const float* __restrict__ fcapT, float* __restrict__ mbuf, float* __restrict__ Abuf,
    float* __restrict__ mf) {
  int bh = threadIdx.x;
  int base = bh * 1024;
  float m = 0.f, A = 0.f;
  for (int t0 = 0; t0 < 1024; t0 += 4) {
    f32x4 fc = *reinterpret_cast<const f32x4*>(fcapT + base + t0);
    f32x4 ic = *reinterpret_cast<const f32x4*>(icapT + base + t0);
    f32x4 mo, Ao;
    #pragma unroll
    for (int u = 0; u < 4; ++u) {
      A = (((t0 + u) & (CH - 1)) == 0) ? fc[u] : A + fc[u];
      m = fmaxf(fc[u] + m, ic[u]);
      mo[u] = m; Ao[u] = A;
    }
    *reinterpret_cast<f32x4*>(mbuf + base + t0) = mo;
    *reinterpret_cast<f32x4*>(Abuf + base + t0) = Ao;
  }
  mf[bh] = m;
}

// ---------------- B1: per-(bh,chunk) intra-chunk attention + chunk summary ----------------
// coefficients: D[t][s] = exp(A_t - A_s + ic_s - m_t) (<=1), 1/sqrt(d) folded in.
__global__ __launch_bounds__(256) void chunk_kernel(
    const bf16* __restrict__ oqkv, const float* __restrict__ icapT,
    const float* __restrict__ mbuf, const float* __restrict__ Abuf,
    bf16* __restrict__ hbuf, bf16* __restrict__ UC, float* __restrict__ nUn,
    float* __restrict__ denp) {
  int bh = blockIdx.x, c = blockIdx.y;
  int b = bh >> 3, h = bh & 7;
  int tid = threadIdx.x, lane = tid & 63, wv = tid >> 6;
  int mh = wv >> 1, nh = wv & 1;
  int rsel = lane & 15, koff = (lane >> 4) * 8;
  int crow = (lane >> 4) * 4, ccol = lane & 15;
  __shared__ float At[CH], mt[CH], colt[CH], wsh[CH], rsw[2][CH];
  __shared__ bf16 P[CH][72];
  __shared__ bf16 Vt[96][72];
  __shared__ bf16 Kw[96][72];
  int t0g = c * CH;
  size_t grow0 = (size_t)(b * 1024 + t0g);
  const int qcol = 768 + h * 96, kcol = 1536 + h * 96, vcol = 2304 + h * 96;
  if (tid < CH) {
    float a  = Abuf[bh * 1024 + t0g + tid];
    float mm = mbuf[bh * 1024 + t0g + tid];
    float ic = icapT[bh * 1024 + t0g + tid];
    At[tid] = a; mt[tid] = mm; colt[tid] = ic - a;
  }
  __syncthreads();
  if (tid < CH) wsh[tid] = INV_SQRT_D * expf((At[CH - 1] - mt[CH - 1]) + colt[tid]);
  __syncthreads();
  // stage V^T and (diag(w) K)^T
  #pragma unroll
  for (int it = 0; it < (CH * 96) / 256; ++it) {
    int idx = tid + it * 256;
    int s = idx / 96, e = idx - s * 96;
    const bf16* rp = oqkv + (grow0 + s) * OQKV_W;
    Vt[e][s] = rp[vcol + e];
    Kw[e][s] = __float2bfloat16(wsh[s] * cvt(rp[kcol + e]));
  }
  // S = Q K^T : wave -> 32x32 tile
  {
    const bf16* aptr = oqkv + (grow0 + mh * 32 + rsel) * OQKV_W + qcol + koff;
    const bf16* wptr = oqkv + (grow0 + nh * 32 + rsel) * OQKV_W + kcol + koff;
    f32x4 sacc[2][2];
    #pragma unroll
    for (int i = 0; i < 2; i++)
      #pragma unroll
      for (int j = 0; j < 2; j++) sacc[i][j] = (f32x4){0.f, 0.f, 0.f, 0.f};
    for (int k0 = 0; k0 < 96; k0 += 32) {
      short8 af[2], bfr[2];
      #pragma unroll
      for (int i = 0; i < 2; i++)
        af[i] = *reinterpret_cast<const short8*>(aptr + (size_t)i * 16 * OQKV_W + k0);
      #pragma unroll
      for (int j = 0; j < 2; j++)
        bfr[j] = *reinterpret_cast<const short8*>(wptr + (size_t)j * 16 * OQKV_W + k0);
      #pragma unroll
      for (int i = 0; i < 2; i++)
        #pragma unroll
        for (int j = 0; j < 2; j++)
          sacc[i][j] = __builtin_amdgcn_mfma_f32_16x16x32_bf16(af[i], bfr[j], sacc[i][j], 0, 0, 0);
    }
    // build P (causal, coef-weighted) + rowsums
    float rsum[2][4] = {};
    #pragma unroll
    for (int i = 0; i < 2; i++)
      #pragma unroll
      for (int j = 0; j < 2; j++) {
        int col = nh * 32 + ccol + j * 16;
        #pragma unroll
        for (int r = 0; r < 4; r++) {
          int row = mh * 32 + crow + i * 16 + r;
          float v = 0.f;
          if (col <= row)
            v = sacc[i][j][r] * (INV_SQRT_D * expf((At[row] - mt[row]) + colt[col]));
          P[row][col] = __float2bfloat16(v);
          rsum[i][r] += v;
        }
      }
    #pragma unroll
    for (int msk = 1; msk < 16; msk <<= 1)
      #pragma unroll
      for (int i = 0; i < 2; i++)
        #pragma unroll
        for (int r = 0; r < 4; r++) rsum[i][r] += __shfl_xor(rsum[i][r], msk);
    if (ccol == 0)
      #pragma unroll
      for (int i = 0; i < 2; i++)
        #pragma unroll
        for (int r = 0; r < 4; r++) rsw[nh][mh * 32 + crow + i * 16 + r] = rsum[i][r];
  }
  __syncthreads();
  if (tid < CH) denp[bh * 1024 + t0g + tid] = rsw[0][tid] + rsw[1][tid];
  // PV: [64 t, 96 d, K=64 s]; wave -> 32x48
  {
    f32x4 pacc[2][3];
    #pragma unroll
    for (int i = 0; i < 2; i++)
      #pragma unroll
      for (int j = 0; j < 3; j++) pacc[i][j] = (f32x4){0.f, 0.f, 0.f, 0.f};
    const bf16* pp = &P[mh * 32 + rsel][0];
    for (int k0 = 0; k0 < CH; k0 += 32) {
      short8 af[2], bfr[3];
      #pragma unroll
      for (int i = 0; i < 2; i++)
        af[i] = *reinterpret_cast<const short8*>(pp + (size_t)i * 16 * 72 + koff + k0);
      #pragma unroll
      for (int j = 0; j < 3; j++)
        bfr[j] = *reinterpret_cast<const short8*>(&Vt[nh * 48 + j * 16 + rsel][0] + koff + k0);
      #pragma unroll
      for (int i = 0; i < 2; i++)
        #pragma unroll
        for (int j = 0; j < 3; j++)
          pacc[i][j] = __builtin_amdgcn_mfma_f32_16x16x32_bf16(af[i], bfr[j], pacc[i][j], 0, 0, 0);
    }
    #pragma unroll
    for (int i = 0; i < 2; i++)
      #pragma unroll
      for (int j = 0; j < 3; j++) {
        int col = nh * 48 + ccol + j * 16;
        #pragma unroll
        for (int r = 0; r < 4; r++) {
          int row = mh * 32 + crow + i * 16 + r;
          hbuf[(grow0 + row) * 768 + h * 96 + col] = __float2bfloat16(pacc[i][j][r]);
        }
      }
  }
  // U[d,e] = sum_s w_s v[s,d] k[s,e] : A=Vt, B=Kw; wave -> 48x48
  {
    f32x4 uacc[3][3];
    #pragma unroll
    for (int i = 0; i < 3; i++)
      #pragma unroll
      for (int j = 0; j < 3; j++) uacc[i][j] = (f32x4){0.f, 0.f, 0.f, 0.f};
    for (int k0 = 0; k0 < CH; k0 += 32) {
      short8 af[3], bfr[3];
      #pragma unroll
      for (int i = 0; i < 3; i++)
        af[i] = *reinterpret_cast<const short8*>(&Vt[mh * 48 + i * 16 + rsel][0] + koff + k0);
      #pragma unroll
      for (int j = 0; j < 3; j++)
        bfr[j] = *reinterpret_cast<const short8*>(&Kw[nh * 48 + j * 16 + rsel][0] + koff + k0);
      #pragma unroll
      for (int i = 0; i < 3; i++)
        #pragma unroll
        for (int j = 0; j < 3; j++)
          uacc[i][j] = __builtin_amdgcn_mfma_f32_16x16x32_bf16(af[i], bfr[j], uacc[i][j], 0, 0, 0);
    }
    size_t ub = ((size_t)c * 64 + bh) * 9216;
    #pragma unroll
    for (int i = 0; i < 3; i++)
      #pragma unroll
      for (int j = 0; j < 3; j++) {
        int e = nh * 48 + ccol + j * 16;
        #pragma unroll
        for (int r = 0; r < 4; r++) {
          int d = mh * 48 + crow + i * 16 + r;
          UC[ub + (size_t)d * 96 + e] = __float2bfloat16(uacc[i][j][r]);
        }
      }
  }
  if (tid < 96) {
    float s = 0.f;
    #pragma unroll 16
    for (int s2 = 0; s2 < CH; ++s2) s += cvt(Kw[tid][s2]);
    nUn[((size_t)c * 64 + bh) * 96 + tid] = s;
  }
}

// ---------------- B2: chunk-boundary C recurrence (in-place U -> Cstart) ----------------
__global__ __launch_bounds__(256) void cscan_kernel(bf16* __restrict__ UC,
    const float* __restrict__ mbuf, const float* __restrict__ Abuf, float* __restrict__ Cf) {
  int bh = blockIdx.y;
  int elem = blockIdx.x * 256 + threadIdx.x;
  if (elem >= 9216) return;
  float cur = 0.f;
  for (int c = 0; c < NCH; ++c) {
    size_t o = ((size_t)c * 64 + bh) * 9216 + elem;
    float u = cvt(UC[o]);
    UC[o] = __float2bfloat16(cur);          // state at START of chunk c
    float mprev = c ? mbuf[bh * 1024 + c * CH - 1] : 0.f;
    float mend  = mbuf[bh * 1024 + c * CH + CH - 1];
    float aend  = Abuf[bh * 1024 + c * CH + CH - 1];
    cur = expf(aend + mprev - mend) * cur + u;
  }
  Cf[(size_t)bh * 9216 + elem] = cur;
}

__global__ __launch_bounds__(128) void nscan_kernel(float* __restrict__ nUn,
    const float* __restrict__ mbuf, const float* __restrict__ Abuf, float* __restrict__ nf) {
  int bh = blockIdx.x, e = threadIdx.x;
  if (e >= 96) return;
  float cur = 1.f;                          // ref: n0 = ones
  for (int c = 0; c < NCH; ++c) {
    size_t o = ((size_t)c * 64 + bh) * 96 + e;
    float u = nUn[o];
    nUn[o] = cur;
    float mprev = c ? mbuf[bh * 1024 + c * CH - 1] : 0.f;
    float mend  = mbuf[bh * 1024 + c * CH + CH - 1];
    float aend  = Abuf[bh * 1024 + c * CH + CH - 1];
    cur = expf(aend + mprev - mend) * cur + u;
  }
  nf[bh * 96 + e] = cur;
}

// ---------------- B3: add carry terms, o-gate, finalize h ----------------
__global__ __launch_bounds__(256) void carry_kernel(
    const bf16* __restrict__ oqkv, const bf16* __restrict__ Cst, const float* __restrict__ nstg,
    const float* __restrict__ mbuf, const float* __restrict__ Abuf,
    const float* __restrict__ denp, bf16* __restrict__ hbuf) {
  int bh = blockIdx.x, c = blockIdx.y;
  int b = bh >> 3, h = bh & 7;
  int tid = threadIdx.x, lane = tid & 63, wv = tid >> 6;
  int mh = wv >> 1, nh = wv & 1;
  int rsel = lane & 15, koff = (lane >> 4) * 8;
  int crow = (lane >> 4) * 4, ccol = lane & 15;
  __shared__ float carry[CH], den[CH], nsh[96];
  __shared__ bf16 osd[CH][104], hp[CH][104];
  int t0g = c * CH;
  size_t grow0 = (size_t)(b * 1024 + t0g);
  float mprev = c ? mbuf[bh * 1024 + t0g - 1] : 0.f;
  if (tid < 96) nsh[tid] = nstg[((size_t)c * 64 + bh) * 96 + tid];
  if (tid < CH)
    carry[tid] = expf(Abuf[bh * 1024 + t0g + tid] + mprev - mbuf[bh * 1024 + t0g + tid]);
  #pragma unroll
  for (int it = 0; it < (CH * 96) / 256; ++it) {
    int idx = tid + it * 256;
    int s = idx / 96, e = idx - s * 96;
    osd[s][e] = oqkv[(grow0 + s) * OQKV_W + h * 96 + e];
    hp[s][e]  = hbuf[(grow0 + s) * 768 + h * 96 + e];
  }
  __syncthreads();
  if (tid < CH) {
    const bf16* qr = oqkv + (grow0 + tid) * OQKV_W + 768 + h * 96;
    float qn = 0.f;
    #pragma unroll 16
    for (int e = 0; e < 96; ++e) qn += cvt(qr[e]) * nsh[e];
    den[tid] = fmaxf(denp[bh * 1024 + t0g + tid] + carry[tid] * qn, 1.f);
  }
  // Qc[t,d] = sum_e q[t,e] Cstart[d,e]; wave -> 32x48
  size_t cb = ((size_t)c * 64 + bh) * 9216;
  const bf16* aptr = oqkv + (grow0 + mh * 32 + rsel) * OQKV_W + 768 + h * 96 + koff;
  f32x4 qa[2][3];
  #pragma unroll
  for (int i = 0; i < 2; i++)
    #pragma unroll
    for (int j = 0; j < 3; j++) qa[i][j] = (f32x4){0.f, 0.f, 0.f, 0.f};
  for (int k0 = 0; k0 < 96; k0 += 32) {
    short8 af[2], bfr[3];
    #pragma unroll
    for (int i = 0; i < 2; i++)
      af[i] = *reinterpret_cast<const short8*>(aptr + (size_t)i * 16 * OQKV_W + k0);
    #pragma unroll
    for (int j = 0; j < 3; j++)
      bfr[j] = *reinterpret_cast<const short8*>(Cst + cb + (size_t)(nh * 48 + j * 16 + rsel) * 96 + koff + k0);
    #pragma unroll
    for (int i = 0; i < 2; i++)
      #pragma unroll
      for (int j = 0; j < 3; j++)
        qa[i][j] = __builtin_amdgcn_mfma_f32_16x16x32_bf16(af[i], bfr[j], qa[i][j], 0, 0, 0);
  }
  __syncthreads();
  #pragma unroll
  for (int i = 0; i < 2; i++)
    #pragma unroll
    for (int j = 0; j < 3; j++) {
      int col = nh * 48 + ccol + j * 16;
      #pragma unroll
      for (int r = 0; r < 4; r++) {
        int row = mh * 32 + crow + i * 16 + r;
        float oc = CAPV * tanhf(cvt(osd[row][col]) * (1.f / CAPV));
        float og = 1.f / (1.f + expf(-oc));
        float hv = og * (cvt(hp[row][col]) + carry[row] * qa[i][j][r]) / den[row];
        hbuf[(grow0 + row) * 768 + h * 96 + col] = __float2bfloat16(hv);
      }
    }
}

extern "C" void kernel_launch(void* const* d_in, const int* in_sizes, int n_in,
                              void* d_out, int out_size, void* d_ws, size_t ws_size,
                              hipStream_t stream) {
  const float* x       = (const float*)d_in[0];
  const float* ln1_g   = (const float*)d_in[1];
  const float* ln1_b   = (const float*)d_in[2];
  const float* W_up_l  = (const float*)d_in[3];
  const float* W_up_r  = (const float*)d_in[4];
  const float* conv_w  = (const float*)d_in[5];
  const float* W_skip  = (const float*)d_in[6];
  const float* fused_W = (const float*)d_in[7];
  const float* fused_b = (const float*)d_in[8];
  const float* ln2_g   = (const float*)d_in[9];
  const float* ln2_b   = (const float*)d_in[10];
  const float* W_down  = (const float*)d_in[11];

  char* ws = (char*)d_ws;
  size_t off = 0;
  auto carve = [&](size_t bytes) -> char* {
    char* p = ws + off;
    off += (bytes + 255) & ~(size_t)255;
    return p;
  };
  bf16* wup    = (bf16*)carve((size_t)NPAD_UP * 768 * 2);
  bf16* wsf2   = (bf16*)carve((size_t)SFW2 * 1536 * 2);
  bf16* wdn    = (bf16*)carve((size_t)768 * 768 * 2);
  float* bias2 = (float*)carve(SFW2 * 4);
  bf16* srt    = (bf16*)carve((size_t)NTOK * 768 * 2);
  bf16* skipb  = (bf16*)carve((size_t)NTOK * 768 * 2);
  float* gates = (float*)carve((size_t)NTOK * 64 * 4);
  bf16* oqkv   = (bf16*)carve((size_t)NTOK * OQKV_W * 2);
  char* xcr    = carve((size_t)NTOK * 1536 * 2);          // 25.2 MB multi-use
  char* R      = carve((size_t)NTOK * 768 * 2 + (size_t)NTOK * NPAD_UP * 2);
  bf16* xn     = (bf16*)R;
  bf16* up_out = (bf16*)(R + (size_t)NTOK * 768 * 2);
  bf16* hbuf   = (bf16*)R;
  bf16* hn     = (bf16*)(R + (size_t)NTOK * 768 * 2);
  // total ~170 MB (same as round 7, known good)

  // phase-A use of xcr: the conv output xc
  bf16* xc = (bf16*)xcr;
  // phase-B reuse of xcr (xc dead after gemm_sf): scan scratch (~20.6 MB <= 25.2 MB)
  size_t o2 = 0;
  auto carve2 = [&](size_t bytes) -> char* {
    char* p = xcr + o2;
    o2 += (bytes + 255) & ~(size_t)255;
    return p;
  };
  float* icapT = (float*)carve2((size_t)65536 * 4);
  float* fcapT = (float*)carve2((size_t)65536 * 4);
  float* mbuf  = (float*)carve2((size_t)65536 * 4);
  float* Abuf  = (float*)carve2((size_t)65536 * 4);
  float* denp  = (float*)carve2((size_t)65536 * 4);
  bf16*  UC    = (bf16*)carve2((size_t)NCH * 64 * 9216 * 2);  // 18.9 MB
  float* nUn   = (float*)carve2((size_t)NCH * 64 * 96 * 4);

  auto blocks = [](long n) { return (unsigned)((n + 255) / 256); };

  long n1 = 1536L * 768, n2 = 768L * 768;
  cast_pad_kernel<<<blocks(n1), 256, 0, stream>>>(W_up_l, wup, n1);
  cast_pad_kernel<<<blocks(n2), 256, 0, stream>>>(W_up_r, wup + n1, n2);
  build_wsf2_kernel<<<dim3(6, SFW2), 256, 0, stream>>>(W_skip, fused_W, wsf2);
  cast_pad_kernel<<<blocks(n2), 256, 0, stream>>>(W_down, wdn, n2);
  build_bias2_kernel<<<blocks(SFW2), 256, 0, stream>>>(fused_b, bias2);

  float* out_f = (float*)d_out;
  float* Cf_out = out_f + YS_ELEMS;
  float* nf_out = Cf_out + (size_t)64 * 9216;
  float* mf_out = nf_out + 64 * 96;

  // phase A
  ln_kernel<float><<<NTOK, 256, 0, stream>>>(x, ln1_g, ln1_b, xn);
  gemm_up_kernel<<<dim3(NPAD_UP / 64, NTOK / 256), 256, 0, stream>>>(
      xn, wup, up_out, NPAD_UP, 768);
  conv_silu_kernel<<<NTOK, 256, 0, stream>>>(up_out, conv_w, xc, srt);
  gemm_sf_kernel<<<dim3(SFW2 / 64, NTOK / 256), 256, 0, stream>>>(
      xc, wsf2, bias2, skipb, gates, oqkv);

  // phase B: chunked parallel mLSTM
  gate_cap_kernel<<<256, 256, 0, stream>>>(gates, icapT, fcapT);
  mscan_kernel<<<1, 64, 0, stream>>>(icapT, fcapT, mbuf, Abuf, mf_out);
  chunk_kernel<<<dim3(64, NCH), 256, 0, stream>>>(
      oqkv, icapT, mbuf, Abuf, hbuf, UC, nUn, denp);
  cscan_kernel<<<dim3(36, 64), 256, 0, stream>>>(UC, mbuf, Abuf, Cf_out);
  nscan_kernel<<<64, 128, 0, stream>>>(nUn, mbuf, Abuf, nf_out);
  carry_kernel<<<dim3(64, NCH), 256, 0, stream>>>(
      oqkv, UC, nUn, mbuf, Abuf, denp, hbuf);

  // phase C
  ln_kernel<bf16><<<NTOK, 256, 0, stream>>>(hbuf, ln2_g, ln2_b, hn);
  gemm_down_kernel<<<dim3(768 / 64, NTOK / 256), 256, 0, stream>>>(
      hn, wdn, skipb, srt, x, out_f);
}

// Round 9
// 591.654 us; speedup vs baseline: 3.3072x; 1.3197x over previous
//
#include <hip/hip_runtime.h>
#include <hip/hip_bf16.h>

#define NH 8
#define NB 8
#define NS 1024
#define NTOK (NB*NS)            // 8192
#define CAPV 15.0f
#define EPSV 1e-6f
#define NPAD_UP 2304            // [W_up_l 1536 | W_up_r 768]
#define SFW3 3968               // [skip 768 | i,f 16 + pad 48 | o,q,k,v 3072 | pad 64]
#define OQKV_W 3072
#define INV_SQRT_D 0.10206207261596575f
#define YS_ELEMS ((size_t)NTOK * 768)   // 6291456
#define CH 64                   // chunk length
#define NCH 16                  // chunks per (b,h)

typedef __attribute__((ext_vector_type(8))) short short8;
typedef __attribute__((ext_vector_type(4))) float f32x4;
typedef __hip_bfloat16 bf16;

__device__ inline float cvt(float v) { return v; }
__device__ inline float cvt(bf16 v) { return __bfloat162float(v); }

// async global->LDS, 16B per lane, dest = wave-uniform base + lane*16
__device__ __forceinline__ void gll16(const void* g, void* l) {
  __builtin_amdgcn_global_load_lds(
      (const __attribute__((address_space(1))) void*)g,
      (__attribute__((address_space(3))) void*)l, 16, 0, 0);
}

// ---------------- weight cast ----------------
__global__ void cast_pad_kernel(const float* __restrict__ src, bf16* __restrict__ dst, long n) {
  long i = (long)blockIdx.x * 256 + threadIdx.x;
  if (i < n) dst[i] = __float2bfloat16(src[i]);
}

// rows [0,768) W_skip | [768,784) fused(i,f) | [784,832) 0 | [832,3904) fused(o,q,k,v) | [3904,3968) 0
__global__ void build_wsf2_kernel(const float* __restrict__ Wskip, const float* __restrict__ fusedW,
                                  bf16* __restrict__ dst) {
  int k = blockIdx.x * 256 + threadIdx.x;   // 0..1535
  int r = blockIdx.y;                        // 0..3967
  float v;
  if (r < 768) v = Wskip[(size_t)r * 1536 + k];
  else if (r < 784) v = fusedW[(size_t)(r - 768) * 1536 + k];
  else if (r < 832) v = 0.f;
  else if (r < 3904) v = fusedW[(size_t)(r - 816) * 1536 + k];
  else v = 0.f;
  dst[(size_t)r * 1536 + k] = __float2bfloat16(v);
}

__global__ void build_bias2_kernel(const float* __restrict__ fb, float* __restrict__ bias) {
  int i = blockIdx.x * 256 + threadIdx.x;
  if (i >= SFW3) return;
  float v = 0.f;
  if (i >= 768 && i < 784) v = fb[i - 768];
  else if (i >= 832 && i < 3904) v = fb[i - 816];
  bias[i] = v;
}

// ---------------- layernorm (768 wide) -> bf16 ----------------
template <typename T>
__global__ __launch_bounds__(256) void ln_kernel(const T* __restrict__ x,
    const float* __restrict__ g, const float* __restrict__ bta, bf16* __restrict__ out) {
  int row = blockIdx.x;
  const T* xr = x + (size_t)row * 768;
  int t = threadIdx.x;
  float v0 = cvt(xr[t]), v1 = cvt(xr[t + 256]), v2 = cvt(xr[t + 512]);
  float ssum = v0 + v1 + v2;
  __shared__ float red[8];
  #pragma unroll
  for (int m = 1; m < 64; m <<= 1) ssum += __shfl_xor(ssum, m);
  int wave = t >> 6, lane = t & 63;
  if (lane == 0) red[wave] = ssum;
  __syncthreads();
  float mu = (red[0] + red[1] + red[2] + red[3]) * (1.0f / 768.0f);
  float d0 = v0 - mu, d1 = v1 - mu, d2 = v2 - mu;
  float sq = d0 * d0 + d1 * d1 + d2 * d2;
  #pragma unroll
  for (int m = 1; m < 64; m <<= 1) sq += __shfl_xor(sq, m);
  if (lane == 0) red[wave + 4] = sq;
  __syncthreads();
  float var = (red[4] + red[5] + red[6] + red[7]) * (1.0f / 768.0f);
  float rs = rsqrtf(var + EPSV);
  size_t o = (size_t)row * 768;
  out[o + t]       = __float2bfloat16(d0 * rs * g[t]       + bta[t]);
  out[o + t + 256] = __float2bfloat16(d1 * rs * g[t + 256] + bta[t + 256]);
  out[o + t + 512] = __float2bfloat16(d2 * rs * g[t + 512] + bta[t + 512]);
}

// ---------------- 128x128 LDS-staged MFMA GEMM core ----------------
// Block = 256 thr (4 waves), each wave a 64x64 quadrant (wr=wv>>1, wc=wv&1).
// LDS layout fragment-major: [kgrp 0..3][row 0..127][8 bf16]; staged via
// global_load_lds (linear dest, permutation folded into per-lane global src).
__device__ __forceinline__ void gemm128_core(
    const bf16* __restrict__ A, const bf16* __restrict__ W, int K,
    bf16* Als, bf16* Bls, f32x4 (&acc)[4][4]) {
  int tid = threadIdx.x;
  int lane = tid & 63, wv = tid >> 6;
  int wr = wv >> 1, wc = wv & 1;
  int n0 = blockIdx.x * 128, m0 = blockIdx.y * 128;
  int rsel = lane & 15, kg = lane >> 4;
  const bf16* gA0 = A + (size_t)(m0 + lane) * K + wv * 8;
  const bf16* gA1 = A + (size_t)(m0 + 64 + lane) * K + wv * 8;
  const bf16* gB0 = W + (size_t)(n0 + lane) * K + wv * 8;
  const bf16* gB1 = W + (size_t)(n0 + 64 + lane) * K + wv * 8;
  char* lA = (char*)Als + wv * 2048;
  char* lB = (char*)Bls + wv * 2048;
  const short8* rA = (const short8*)((char*)Als + kg * 2048 + (wr * 64 + rsel) * 16);
  const short8* rB = (const short8*)((char*)Bls + kg * 2048 + (wc * 64 + rsel) * 16);
  #pragma unroll
  for (int i = 0; i < 4; i++)
    #pragma unroll
    for (int j = 0; j < 4; j++) acc[i][j] = (f32x4){0.f, 0.f, 0.f, 0.f};
  for (int k0 = 0; k0 < K; k0 += 32) {
    gll16(gA0 + k0, lA);
    gll16(gA1 + k0, lA + 1024);
    gll16(gB0 + k0, lB);
    gll16(gB1 + k0, lB + 1024);
    __syncthreads();                      // drains vmcnt -> staged data visible
    short8 af[4], bw[4];
    #pragma unroll
    for (int i = 0; i < 4; i++) af[i] = rA[i * 16];
    #pragma unroll
    for (int j = 0; j < 4; j++) bw[j] = rB[j * 16];
    #pragma unroll
    for (int i = 0; i < 4; i++)
      #pragma unroll
      for (int j = 0; j < 4; j++)
        acc[i][j] = __builtin_amdgcn_mfma_f32_16x16x32_bf16(af[i], bw[j], acc[i][j], 0, 0, 0);
    __syncthreads();                      // protect LDS from next-step staging
  }
}

#define EPI_BASES                                              \
  int lane = threadIdx.x & 63, wv = threadIdx.x >> 6;          \
  int crow_base = blockIdx.y * 128 + (wv >> 1) * 64 + (lane >> 4) * 4; \
  int ccol_base = blockIdx.x * 128 + (wv & 1) * 64 + (lane & 15);

__global__ __launch_bounds__(256) void gemm_up_kernel(const bf16* __restrict__ A,
    const bf16* __restrict__ W, bf16* __restrict__ C, int N, int K) {
  __shared__ bf16 Als[4096], Bls[4096];
  f32x4 acc[4][4];
  gemm128_core(A, W, K, Als, Bls, acc);
  EPI_BASES
  #pragma unroll
  for (int i = 0; i < 4; i++)
    #pragma unroll
    for (int j = 0; j < 4; j++) {
      int col = ccol_base + j * 16;
      #pragma unroll
      for (int r = 0; r < 4; r++)
        C[(size_t)(crow_base + i * 16 + r) * N + col] = __float2bfloat16(acc[i][j][r]);
    }
}

__global__ __launch_bounds__(256) void gemm_sf_kernel(const bf16* __restrict__ A,
    const bf16* __restrict__ W, const float* __restrict__ bias,
    bf16* __restrict__ skipb, float* __restrict__ gates, bf16* __restrict__ oqkv) {
  __shared__ bf16 Als[4096], Bls[4096];
  f32x4 acc[4][4];
  gemm128_core(A, W, 1536, Als, Bls, acc);
  EPI_BASES
  #pragma unroll
  for (int i = 0; i < 4; i++)
    #pragma unroll
    for (int j = 0; j < 4; j++) {
      int col = ccol_base + j * 16;
      float bv = bias[col];
      #pragma unroll
      for (int r = 0; r < 4; r++) {
        int row = crow_base + i * 16 + r;
        float v = acc[i][j][r] + bv;
        if (col < 768)        skipb[(size_t)row * 768 + col] = __float2bfloat16(v);
        else if (col < 832)   gates[(size_t)row * 64 + (col - 768)] = v;
        else if (col < 3904)  oqkv[(size_t)row * OQKV_W + (col - 832)] = __float2bfloat16(v);
      }
    }
}

__global__ __launch_bounds__(256) void gemm_down_kernel(const bf16* __restrict__ A,
    const bf16* __restrict__ W, const bf16* __restrict__ skipb, const bf16* __restrict__ srt,
    const float* __restrict__ x, float* __restrict__ ys) {
  __shared__ bf16 Als[4096], Bls[4096];
  f32x4 acc[4][4];
  gemm128_core(A, W, 768, Als, Bls, acc);
  EPI_BASES
  #pragma unroll
  for (int i = 0; i < 4; i++)
    #pragma unroll
    for (int j = 0; j < 4; j++) {
      int col = ccol_base + j * 16;
      #pragma unroll
      for (int r = 0; r < 4; r++) {
        size_t idx = (size_t)(crow_base + i * 16 + r) * 768 + col;
        ys[idx] = (acc[i][j][r] + cvt(skipb[idx])) * cvt(srt[idx]) + x[idx];
      }
    }
}

// ---------------- causal feature conv + silu; silu(rt) ----------------
__global__ __launch_bounds__(256) void conv_silu_kernel(const bf16* __restrict__ up,
    const float* __restrict__ cw, bf16* __restrict__ xc, bf16* __restrict__ srt) {
  int row = blockIdx.x;
  const bf16* xr = up + (size_t)row * NPAD_UP;
  float w0 = cw[0], w1 = cw[1], w2 = cw[2], w3 = cw[3];
  int t = threadIdx.x;
  #pragma unroll
  for (int u = 0; u < 6; ++u) {
    int j = t + u * 256;
    float xm3 = j >= 3 ? cvt(xr[j - 3]) : 0.f;
    float xm2 = j >= 2 ? cvt(xr[j - 2]) : 0.f;
    float xm1 = j >= 1 ? cvt(xr[j - 1]) : 0.f;
    float x0  = cvt(xr[j]);
    float c = w0 * xm3 + w1 * xm2 + w2 * xm1 + w3 * x0;
    xc[(size_t)row * 1536 + j] = __float2bfloat16(c / (1.f + expf(-c)));
  }
  #pragma unroll
  for (int u = 0; u < 3; ++u) {
    int j = t + u * 256;
    float r = cvt(xr[1536 + j]);
    srt[(size_t)row * 768 + j] = __float2bfloat16(r / (1.f + expf(-r)));
  }
}

// ---------------- B0a: cap gates, transpose to [bh][t] ----------------
__global__ __launch_bounds__(256) void gate_cap_kernel(const float* __restrict__ gates,
    float* __restrict__ icapT, float* __restrict__ fcapT) {
  int idx = blockIdx.x * 256 + threadIdx.x;   // 0..65535
  int bh = idx >> 10, t = idx & 1023;
  int b = bh >> 3, h = bh & 7;
  size_t row = (size_t)(b * 1024 + t) * 64;
  icapT[idx] = CAPV * tanhf(gates[row + h] * (1.f / CAPV));
  fcapT[idx] = CAPV * tanhf(gates[row + 8 + h] * (1.f / CAPV));
}

// ---------------- B0b: sequential m-scan + per-chunk A cumsum (lane = bh) ----------------
__global__ __launch_bounds__(64) void mscan_kernel(const float* __restrict__ icapT,
    const float* __restrict__ fcapT, float* __restrict__ mbuf, float* __restrict__ Abuf,
    float* __restrict__ mf) {
  int bh = threadIdx.x;
  int base = bh * 1024;
  float m = 0.f, A = 0.f;
  for (int t0 = 0; t0 < 1024; t0 += 4) {
    f32x4 fc = *reinterpret_cast<const f32x4*>(fcapT + base + t0);
    f32x4 ic = *reinterpret_cast<const f32x4*>(icapT + base + t0);
    f32x4 mo, Ao;
    #pragma unroll
    for (int u = 0; u < 4; ++u) {
      A = (((t0 + u) & (CH - 1)) == 0) ? fc[u] : A + fc[u];
      m = fmaxf(fc[u] + m, ic[u]);
      mo[u] = m; Ao[u] = A;
    }
    *reinterpret_cast<f32x4*>(mbuf + base + t0) = mo;
    *reinterpret_cast<f32x4*>(Abuf + base + t0) = Ao;
  }
  mf[bh] = m;
}

// ---------------- B1: per-(bh,chunk) intra-chunk attention + chunk summary ----------------
__global__ __launch_bounds__(256) void chunk_kernel(
    const bf16* __restrict__ oqkv, const float* __restrict__ icapT,
    const float* __restrict__ mbuf, const float* __restrict__ Abuf,
    bf16* __restrict__ hbuf, bf16* __restrict__ UC, float* __restrict__ nUn,
    float* __restrict__ denp) {
  int bh = blockIdx.x, c = blockIdx.y;
  int b = bh >> 3, h = bh & 7;
  int tid = threadIdx.x, lane = tid & 63, wv = tid >> 6;
  int mh = wv >> 1, nh = wv & 1;
  int rsel = lane & 15, koff = (lane >> 4) * 8;
  int crow = (lane >> 4) * 4, ccol = lane & 15;
  __shared__ float At[CH], mt[CH], colt[CH], wsh[CH], rsw[2][CH];
  __shared__ bf16 P[CH][72];
  __shared__ bf16 Vt[96][72];
  __shared__ bf16 Kw[96][72];
  int t0g = c * CH;
  size_t grow0 = (size_t)(b * 1024 + t0g);
  const int qcol = 768 + h * 96, kcol = 1536 + h * 96, vcol = 2304 + h * 96;
  if (tid < CH) {
    float a  = Abuf[bh * 1024 + t0g + tid];
    float mm = mbuf[bh * 1024 + t0g + tid];
    float ic = icapT[bh * 1024 + t0g + tid];
    At[tid] = a; mt[tid] = mm; colt[tid] = ic - a;
  }
  __syncthreads();
  if (tid < CH) wsh[tid] = INV_SQRT_D * expf((At[CH - 1] - mt[CH - 1]) + colt[tid]);
  __syncthreads();
  #pragma unroll
  for (int it = 0; it < (CH * 96) / 256; ++it) {
    int idx = tid + it * 256;
    int s = idx / 96, e = idx - s * 96;
    const bf16* rp = oqkv + (grow0 + s) * OQKV_W;
    Vt[e][s] = rp[vcol + e];
    Kw[e][s] = __float2bfloat16(wsh[s] * cvt(rp[kcol + e]));
  }
  // S = Q K^T : wave -> 32x32 tile
  {
    const bf16* aptr = oqkv + (grow0 + mh * 32 + rsel) * OQKV_W + qcol + koff;
    const bf16* wptr = oqkv + (grow0 + nh * 32 + rsel) * OQKV_W + kcol + koff;
    f32x4 sacc[2][2];
    #pragma unroll
    for (int i = 0; i < 2; i++)
      #pragma unroll
      for (int j = 0; j < 2; j++) sacc[i][j] = (f32x4){0.f, 0.f, 0.f, 0.f};
    for (int k0 = 0; k0 < 96; k0 += 32) {
      short8 af[2], bfr[2];
      #pragma unroll
      for (int i = 0; i < 2; i++)
        af[i] = *reinterpret_cast<const short8*>(aptr + (size_t)i * 16 * OQKV_W + k0);
      #pragma unroll
      for (int j = 0; j < 2; j++)
        bfr[j] = *reinterpret_cast<const short8*>(wptr + (size_t)j * 16 * OQKV_W + k0);
      #pragma unroll
      for (int i = 0; i < 2; i++)
        #pragma unroll
        for (int j = 0; j < 2; j++)
          sacc[i][j] = __builtin_amdgcn_mfma_f32_16x16x32_bf16(af[i], bfr[j], sacc[i][j], 0, 0, 0);
    }
    float rsum[2][4] = {};
    #pragma unroll
    for (int i = 0; i < 2; i++)
      #pragma unroll
      for (int j = 0; j < 2; j++) {
        int col = nh * 32 + ccol + j * 16;
        #pragma unroll
        for (int r = 0; r < 4; r++) {
          int row = mh * 32 + crow + i * 16 + r;
          float v = 0.f;
          if (col <= row)
            v = sacc[i][j][r] * (INV_SQRT_D * expf((At[row] - mt[row]) + colt[col]));
          P[row][col] = __float2bfloat16(v);
          rsum[i][r] += v;
        }
      }
    #pragma unroll
    for (int msk = 1; msk < 16; msk <<= 1)
      #pragma unroll
      for (int i = 0; i < 2; i++)
        #pragma unroll
        for (int r = 0; r < 4; r++) rsum[i][r] += __shfl_xor(rsum[i][r], msk);
    if (ccol == 0)
      #pragma unroll
      for (int i = 0; i < 2; i++)
        #pragma unroll
        for (int r = 0; r < 4; r++) rsw[nh][mh * 32 + crow + i * 16 + r] = rsum[i][r];
  }
  __syncthreads();
  if (tid < CH) denp[bh * 1024 + t0g + tid] = rsw[0][tid] + rsw[1][tid];
  // PV
  {
    f32x4 pacc[2][3];
    #pragma unroll
    for (int i = 0; i < 2; i++)
      #pragma unroll
      for (int j = 0; j < 3; j++) pacc[i][j] = (f32x4){0.f, 0.f, 0.f, 0.f};
    const bf16* pp = &P[mh * 32 + rsel][0];
    for (int k0 = 0; k0 < CH; k0 += 32) {
      short8 af[2], bfr[3];
      #pragma unroll
      for (int i = 0; i < 2; i++)
        af[i] = *reinterpret_cast<const short8*>(pp + (size_t)i * 16 * 72 + koff + k0);
      #pragma unroll
      for (int j = 0; j < 3; j++)
        bfr[j] = *reinterpret_cast<const short8*>(&Vt[nh * 48 + j * 16 + rsel][0] + koff + k0);
      #pragma unroll
      for (int i = 0; i < 2; i++)
        #pragma unroll
        for (int j = 0; j < 3; j++)
          pacc[i][j] = __builtin_amdgcn_mfma_f32_16x16x32_bf16(af[i], bfr[j], pacc[i][j], 0, 0, 0);
    }
    #pragma unroll
    for (int i = 0; i < 2; i++)
      #pragma unroll
      for (int j = 0; j < 3; j++) {
        int col = nh * 48 + ccol + j * 16;
        #pragma unroll
        for (int r = 0; r < 4; r++) {
          int row = mh * 32 + crow + i * 16 + r;
          hbuf[(grow0 + row) * 768 + h * 96 + col] = __float2bfloat16(pacc[i][j][r]);
        }
      }
  }
  // U = V^T diag(w) K
  {
    f32x4 uacc[3][3];
    #pragma unroll
    for (int i = 0; i < 3; i++)
      #pragma unroll
      for (int j = 0; j < 3; j++) uacc[i][j] = (f32x4){0.f, 0.f, 0.f, 0.f};
    for (int k0 = 0; k0 < CH; k0 += 32) {
      short8 af[3], bfr[3];
      #pragma unroll
      for (int i = 0; i < 3; i++)
        af[i] = *reinterpret_cast<const short8*>(&Vt[mh * 48 + i * 16 + rsel][0] + koff + k0);
      #pragma unroll
      for (int j = 0; j < 3; j++)
        bfr[j] = *reinterpret_cast<const short8*>(&Kw[nh * 48 + j * 16 + rsel][0] + koff + k0);
      #pragma unroll
      for (int i = 0; i < 3; i++)
        #pragma unroll
        for (int j = 0; j < 3; j++)
          uacc[i][j] = __builtin_amdgcn_mfma_f32_16x16x32_bf16(af[i], bfr[j], uacc[i][j], 0, 0, 0);
    }
    size_t ub = ((size_t)c * 64 + bh) * 9216;
    #pragma unroll
    for (int i = 0; i < 3; i++)
      #pragma unroll
      for (int j = 0; j < 3; j++) {
        int e = nh * 48 + ccol + j * 16;
        #pragma unroll
        for (int r = 0; r < 4; r++) {
          int d = mh * 48 + crow + i * 16 + r;
          UC[ub + (size_t)d * 96 + e] = __float2bfloat16(uacc[i][j][r]);
        }
      }
  }
  if (tid < 96) {
    float s = 0.f;
    #pragma unroll 16
    for (int s2 = 0; s2 < CH; ++s2) s += cvt(Kw[tid][s2]);
    nUn[((size_t)c * 64 + bh) * 96 + tid] = s;
  }
}

// ---------------- B2: chunk-boundary C recurrence (in-place U -> Cstart) ----------------
__global__ __launch_bounds__(256) void cscan_kernel(bf16* __restrict__ UC,
    const float* __restrict__ mbuf, const float* __restrict__ Abuf, float* __restrict__ Cf) {
  int bh = blockIdx.y;
  int elem = blockIdx.x * 256 + threadIdx.x;
  if (elem >= 9216) return;
  float cur = 0.f;
  for (int c = 0; c < NCH; ++c) {
    size_t o = ((size_t)c * 64 + bh) * 9216 + elem;
    float u = cvt(UC[o]);
    UC[o] = __float2bfloat16(cur);
    float mprev = c ? mbuf[bh * 1024 + c * CH - 1] : 0.f;
    float mend  = mbuf[bh * 1024 + c * CH + CH - 1];
    float aend  = Abuf[bh * 1024 + c * CH + CH - 1];
    cur = expf(aend + mprev - mend) * cur + u;
  }
  Cf[(size_t)bh * 9216 + elem] = cur;
}

__global__ __launch_bounds__(128) void nscan_kernel(float* __restrict__ nUn,
    const float* __restrict__ mbuf, const float* __restrict__ Abuf, float* __restrict__ nf) {
  int bh = blockIdx.x, e = threadIdx.x;
  if (e >= 96) return;
  float cur = 1.f;
  for (int c = 0; c < NCH; ++c) {
    size_t o = ((size_t)c * 64 + bh) * 96 + e;
    float u = nUn[o];
    nUn[o] = cur;
    float mprev = c ? mbuf[bh * 1024 + c * CH - 1] : 0.f;
    float mend  = mbuf[bh * 1024 + c * CH + CH - 1];
    float aend  = Abuf[bh * 1024 + c * CH + CH - 1];
    cur = expf(aend + mprev - mend) * cur + u;
  }
  nf[bh * 96 + e] = cur;
}

// ---------------- B3: add carry terms, o-gate, finalize h ----------------
__global__ __launch_bounds__(256) void carry_kernel(
    const bf16* __restrict__ oqkv, const bf16* __restrict__ Cst, const float* __restrict__ nstg,
    const float* __restrict__ mbuf, const float* __restrict__ Abuf,
    const float* __restrict__ denp, bf16* __restrict__ hbuf) {
  int bh = blockIdx.x, c = blockIdx.y;
  int b = bh >> 3, h = bh & 7;
  int tid = threadIdx.x, lane = tid & 63, wv = tid >> 6;
  int mh = wv >> 1, nh = wv & 1;
  int rsel = lane & 15, koff = (lane >> 4) * 8;
  int crow = (lane >> 4) * 4, ccol = lane & 15;
  __shared__ float carry[CH], den[CH], nsh[96];
  __shared__ bf16 osd[CH][104], hp[CH][104];
  int t0g = c * CH;
  size_t grow0 = (size_t)(b * 1024 + t0g);
  float mprev = c ? mbuf[bh * 1024 + t0g - 1] : 0.f;
  if (tid < 96) nsh[tid] = nstg[((size_t)c * 64 + bh) * 96 + tid];
  if (tid < CH)
    carry[tid] = expf(Abuf[bh * 1024 + t0g + tid] + mprev - mbuf[bh * 1024 + t0g + tid]);
  #pragma unroll
  for (int it = 0; it < (CH * 96) / 256; ++it) {
    int idx = tid + it * 256;
    int s = idx / 96, e = idx - s * 96;
    osd[s][e] = oqkv[(grow0 + s) * OQKV_W + h * 96 + e];
    hp[s][e]  = hbuf[(grow0 + s) * 768 + h * 96 + e];
  }
  __syncthreads();
  if (tid < CH) {
    const bf16* qr = oqkv + (grow0 + tid) * OQKV_W + 768 + h * 96;
    float qn = 0.f;
    #pragma unroll 16
    for (int e = 0; e < 96; ++e) qn += cvt(qr[e]) * nsh[e];
    den[tid] = fmaxf(denp[bh * 1024 + t0g + tid] + carry[tid] * qn, 1.f);
  }
  size_t cb = ((size_t)c * 64 + bh) * 9216;
  const bf16* aptr = oqkv + (grow0 + mh * 32 + rsel) * OQKV_W + 768 + h * 96 + koff;
  f32x4 qa[2][3];
  #pragma unroll
  for (int i = 0; i < 2; i++)
    #pragma unroll
    for (int j = 0; j < 3; j++) qa[i][j] = (f32x4){0.f, 0.f, 0.f, 0.f};
  for (int k0 = 0; k0 < 96; k0 += 32) {
    short8 af[2], bfr[3];
    #pragma unroll
    for (int i = 0; i < 2; i++)
      af[i] = *reinterpret_cast<const short8*>(aptr + (size_t)i * 16 * OQKV_W + k0);
    #pragma unroll
    for (int j = 0; j < 3; j++)
      bfr[j] = *reinterpret_cast<const short8*>(Cst + cb + (size_t)(nh * 48 + j * 16 + rsel) * 96 + koff + k0);
    #pragma unroll
    for (int i = 0; i < 2; i++)
      #pragma unroll
      for (int j = 0; j < 3; j++)
        qa[i][j] = __builtin_amdgcn_mfma_f32_16x16x32_bf16(af[i], bfr[j], qa[i][j], 0, 0, 0);
  }
  __syncthreads();
  #pragma unroll
  for (int i = 0; i < 2; i++)
    #pragma unroll
    for (int j = 0; j < 3; j++) {
      int col = nh * 48 + ccol + j * 16;
      #pragma unroll
      for (int r = 0; r < 4; r++) {
        int row = mh * 32 + crow + i * 16 + r;
        float oc = CAPV * tanhf(cvt(osd[row][col]) * (1.f / CAPV));
        float og = 1.f / (1.f + expf(-oc));
        float hv = og * (cvt(hp[row][col]) + carry[row] * qa[i][j][r]) / den[row];
        hbuf[(grow0 + row) * 768 + h * 96 + col] = __float2bfloat16(hv);
      }
    }
}

extern "C" void kernel_launch(void* const* d_in, const int* in_sizes, int n_in,
                              void* d_out, int out_size, void* d_ws, size_t ws_size,
                              hipStream_t stream) {
  const float* x       = (const float*)d_in[0];
  const float* ln1_g   = (const float*)d_in[1];
  const float* ln1_b   = (const float*)d_in[2];
  const float* W_up_l  = (const float*)d_in[3];
  const float* W_up_r  = (const float*)d_in[4];
  const float* conv_w  = (const float*)d_in[5];
  const float* W_skip  = (const float*)d_in[6];
  const float* fused_W = (const float*)d_in[7];
  const float* fused_b = (const float*)d_in[8];
  const float* ln2_g   = (const float*)d_in[9];
  const float* ln2_b   = (const float*)d_in[10];
  const float* W_down  = (const float*)d_in[11];

  char* ws = (char*)d_ws;
  size_t off = 0;
  auto carve = [&](size_t bytes) -> char* {
    char* p = ws + off;
    off += (bytes + 255) & ~(size_t)255;
    return p;
  };
  bf16* wup    = (bf16*)carve((size_t)NPAD_UP * 768 * 2);
  bf16* wsf2   = (bf16*)carve((size_t)SFW3 * 1536 * 2);
  bf16* wdn    = (bf16*)carve((size_t)768 * 768 * 2);
  float* bias2 = (float*)carve(SFW3 * 4);
  bf16* srt    = (bf16*)carve((size_t)NTOK * 768 * 2);
  bf16* skipb  = (bf16*)carve((size_t)NTOK * 768 * 2);
  float* gates = (float*)carve((size_t)NTOK * 64 * 4);
  bf16* oqkv   = (bf16*)carve((size_t)NTOK * OQKV_W * 2);
  char* xcr    = carve((size_t)NTOK * 1536 * 2);          // 25.2 MB multi-use
  char* R      = carve((size_t)NTOK * 768 * 2 + (size_t)NTOK * NPAD_UP * 2);
  bf16* xn     = (bf16*)R;
  bf16* up_out = (bf16*)(R + (size_t)NTOK * 768 * 2);
  bf16* hbuf   = (bf16*)R;
  bf16* hn     = (bf16*)(R + (size_t)NTOK * 768 * 2);

  bf16* xc = (bf16*)xcr;
  size_t o2 = 0;
  auto carve2 = [&](size_t bytes) -> char* {
    char* p = xcr + o2;
    o2 += (bytes + 255) & ~(size_t)255;
    return p;
  };
  float* icapT = (float*)carve2((size_t)65536 * 4);
  float* fcapT = (float*)carve2((size_t)65536 * 4);
  float* mbuf  = (float*)carve2((size_t)65536 * 4);
  float* Abuf  = (float*)carve2((size_t)65536 * 4);
  float* denp  = (float*)carve2((size_t)65536 * 4);
  bf16*  UC    = (bf16*)carve2((size_t)NCH * 64 * 9216 * 2);
  float* nUn   = (float*)carve2((size_t)NCH * 64 * 96 * 4);

  auto blocks = [](long n) { return (unsigned)((n + 255) / 256); };

  long n1 = 1536L * 768, n2 = 768L * 768;
  cast_pad_kernel<<<blocks(n1), 256, 0, stream>>>(W_up_l, wup, n1);
  cast_pad_kernel<<<blocks(n2), 256, 0, stream>>>(W_up_r, wup + n1, n2);
  build_wsf2_kernel<<<dim3(6, SFW3), 256, 0, stream>>>(W_skip, fused_W, wsf2);
  cast_pad_kernel<<<blocks(n2), 256, 0, stream>>>(W_down, wdn, n2);
  build_bias2_kernel<<<blocks(SFW3), 256, 0, stream>>>(fused_b, bias2);

  float* out_f = (float*)d_out;
  float* Cf_out = out_f + YS_ELEMS;
  float* nf_out = Cf_out + (size_t)64 * 9216;
  float* mf_out = nf_out + 64 * 96;

  // phase A
  ln_kernel<float><<<NTOK, 256, 0, stream>>>(x, ln1_g, ln1_b, xn);
  gemm_up_kernel<<<dim3(NPAD_UP / 128, NTOK / 128), 256, 0, stream>>>(
      xn, wup, up_out, NPAD_UP, 768);
  conv_silu_kernel<<<NTOK, 256, 0, stream>>>(up_out, conv_w, xc, srt);
  gemm_sf_kernel<<<dim3(SFW3 / 128, NTOK / 128), 256, 0, stream>>>(
      xc, wsf2, bias2, skipb, gates, oqkv);

  // phase B: chunked parallel mLSTM
  gate_cap_kernel<<<256, 256, 0, stream>>>(gates, icapT, fcapT);
  mscan_kernel<<<1, 64, 0, stream>>>(icapT, fcapT, mbuf, Abuf, mf_out);
  chunk_kernel<<<dim3(64, NCH), 256, 0, stream>>>(
      oqkv, icapT, mbuf, Abuf, hbuf, UC, nUn, denp);
  cscan_kernel<<<dim3(36, 64), 256, 0, stream>>>(UC, mbuf, Abuf, Cf_out);
  nscan_kernel<<<64, 128, 0, stream>>>(nUn, mbuf, Abuf, nf_out);
  carry_kernel<<<dim3(64, NCH), 256, 0, stream>>>(
      oqkv, UC, nUn, mbuf, Abuf, denp, hbuf);

  // phase C
  ln_kernel<bf16><<<NTOK, 256, 0, stream>>>(hbuf, ln2_g, ln2_b, hn);
  gemm_down_kernel<<<dim3(768 / 128, NTOK / 128), 256, 0, stream>>>(
      hn, wdn, skipb, srt, x, out_f);
}

// Round 10
// 575.455 us; speedup vs baseline: 3.4003x; 1.0281x over previous
//
#include <hip/hip_runtime.h>
#include <hip/hip_bf16.h>

#define NH 8
#define NB 8
#define NS 1024
#define NTOK (NB*NS)            // 8192
#define CAPV 15.0f
#define EPSV 1e-6f
#define NPAD_UP 2304            // [W_up_l 1536 | W_up_r 768]
#define SFW3 3968               // [skip 768 | i,f 16 + pad 48 | o,q,k,v 3072 | pad 64]
#define OQKV_W 3072
#define INV_SQRT_D 0.10206207261596575f
#define YS_ELEMS ((size_t)NTOK * 768)   // 6291456
#define CH 64                   // chunk length
#define NCH 16                  // chunks per (b,h)

typedef __attribute__((ext_vector_type(8))) short short8;
typedef __attribute__((ext_vector_type(4))) float f32x4;
typedef __hip_bfloat16 bf16;

__device__ inline float cvt(float v) { return v; }
__device__ inline float cvt(bf16 v) { return __bfloat162float(v); }

// async global->LDS, 16B per lane, dest = wave-uniform base + lane*16
__device__ __forceinline__ void gll16(const void* g, void* l) {
  __builtin_amdgcn_global_load_lds(
      (const __attribute__((address_space(1))) void*)g,
      (__attribute__((address_space(3))) void*)l, 16, 0, 0);
}

// XCD-aware supertile remap. REQUIRES gridDim.y == 64 (8 XCD x 8 M-rows) and
// gridDim.x*gridDim.y % 8 == 0. XCD k owns M-rows [8k,8k+8), walks N with the
// 8 same-W blocks adjacent in dispatch order -> W-tile L2-resident per XCD.
__device__ __forceinline__ void remap_grid(int& m0, int& n0) {
  int b = blockIdx.y * gridDim.x + blockIdx.x;
  int xcd = b & 7, slot = b >> 3;
  m0 = (xcd * 8 + (slot & 7)) * 128;
  n0 = (slot >> 3) * 128;
}

// ---------------- weight cast ----------------
__global__ void cast_pad_kernel(const float* __restrict__ src, bf16* __restrict__ dst, long n) {
  long i = (long)blockIdx.x * 256 + threadIdx.x;
  if (i < n) dst[i] = __float2bfloat16(src[i]);
}

// rows [0,768) W_skip | [768,784) fused(i,f) | [784,832) 0 | [832,3904) fused(o,q,k,v) | [3904,3968) 0
__global__ void build_wsf2_kernel(const float* __restrict__ Wskip, const float* __restrict__ fusedW,
                                  bf16* __restrict__ dst) {
  int k = blockIdx.x * 256 + threadIdx.x;   // 0..1535
  int r = blockIdx.y;                        // 0..3967
  float v;
  if (r < 768) v = Wskip[(size_t)r * 1536 + k];
  else if (r < 784) v = fusedW[(size_t)(r - 768) * 1536 + k];
  else if (r < 832) v = 0.f;
  else if (r < 3904) v = fusedW[(size_t)(r - 816) * 1536 + k];
  else v = 0.f;
  dst[(size_t)r * 1536 + k] = __float2bfloat16(v);
}

__global__ void build_bias2_kernel(const float* __restrict__ fb, float* __restrict__ bias) {
  int i = blockIdx.x * 256 + threadIdx.x;
  if (i >= SFW3) return;
  float v = 0.f;
  if (i >= 768 && i < 784) v = fb[i - 768];
  else if (i >= 832 && i < 3904) v = fb[i - 816];
  bias[i] = v;
}

// ---------------- layernorm (768 wide) -> bf16 ----------------
template <typename T>
__global__ __launch_bounds__(256) void ln_kernel(const T* __restrict__ x,
    const float* __restrict__ g, const float* __restrict__ bta, bf16* __restrict__ out) {
  int row = blockIdx.x;
  const T* xr = x + (size_t)row * 768;
  int t = threadIdx.x;
  float v0 = cvt(xr[t]), v1 = cvt(xr[t + 256]), v2 = cvt(xr[t + 512]);
  float ssum = v0 + v1 + v2;
  __shared__ float red[8];
  #pragma unroll
  for (int m = 1; m < 64; m <<= 1) ssum += __shfl_xor(ssum, m);
  int wave = t >> 6, lane = t & 63;
  if (lane == 0) red[wave] = ssum;
  __syncthreads();
  float mu = (red[0] + red[1] + red[2] + red[3]) * (1.0f / 768.0f);
  float d0 = v0 - mu, d1 = v1 - mu, d2 = v2 - mu;
  float sq = d0 * d0 + d1 * d1 + d2 * d2;
  #pragma unroll
  for (int m = 1; m < 64; m <<= 1) sq += __shfl_xor(sq, m);
  if (lane == 0) red[wave + 4] = sq;
  __syncthreads();
  float var = (red[4] + red[5] + red[6] + red[7]) * (1.0f / 768.0f);
  float rs = rsqrtf(var + EPSV);
  size_t o = (size_t)row * 768;
  out[o + t]       = __float2bfloat16(d0 * rs * g[t]       + bta[t]);
  out[o + t + 256] = __float2bfloat16(d1 * rs * g[t + 256] + bta[t + 256]);
  out[o + t + 512] = __float2bfloat16(d2 * rs * g[t + 512] + bta[t + 512]);
}

// ---------------- 128x128 LDS-staged MFMA GEMM core, double-buffered ----------------
// Block = 256 thr (4 waves), each wave a 64x64 quadrant. LDS fragment-major
// [buf][kgrp][row][8]. Counted vmcnt(4) keeps next tile's 4 gll16 in flight
// across raw s_barriers (no vmcnt(0) drain in steady state).
__device__ __forceinline__ void gemm128_core(
    const bf16* __restrict__ A, const bf16* __restrict__ W, int K,
    bf16* Als, bf16* Bls, f32x4 (&acc)[4][4], int m0, int n0) {
  int tid = threadIdx.x;
  int lane = tid & 63, wv = tid >> 6;
  int wr = wv >> 1, wc = wv & 1;
  int rsel = lane & 15, kg = lane >> 4;
  const bf16* gA0 = A + (size_t)(m0 + lane) * K + wv * 8;
  const bf16* gA1 = A + (size_t)(m0 + 64 + lane) * K + wv * 8;
  const bf16* gB0 = W + (size_t)(n0 + lane) * K + wv * 8;
  const bf16* gB1 = W + (size_t)(n0 + 64 + lane) * K + wv * 8;
  char* lAb = (char*)Als + wv * 2048;
  char* lBb = (char*)Bls + wv * 2048;
  const char* rAb = (char*)Als + kg * 2048 + (wr * 64 + rsel) * 16;
  const char* rBb = (char*)Bls + kg * 2048 + (wc * 64 + rsel) * 16;
  #pragma unroll
  for (int i = 0; i < 4; i++)
    #pragma unroll
    for (int j = 0; j < 4; j++) acc[i][j] = (f32x4){0.f, 0.f, 0.f, 0.f};
  int NK = K >> 5;
  // prologue: stage tile 0 into buf 0
  gll16(gA0, lAb);
  gll16(gA1, lAb + 1024);
  gll16(gB0, lBb);
  gll16(gB1, lBb + 1024);
  for (int k = 0; k < NK; ++k) {
    int cur = (k & 1) * 8192;
    if (k + 1 < NK) {
      int nxt = ((k + 1) & 1) * 8192;
      int k0 = (k + 1) << 5;
      gll16(gA0 + k0, lAb + nxt);
      gll16(gA1 + k0, lAb + nxt + 1024);
      gll16(gB0 + k0, lBb + nxt);
      gll16(gB1 + k0, lBb + nxt + 1024);
      asm volatile("s_waitcnt vmcnt(4)" ::: "memory");   // tile k landed; k+1 in flight
    } else {
      asm volatile("s_waitcnt vmcnt(0)" ::: "memory");
    }
    __builtin_amdgcn_s_barrier();
    asm volatile("" ::: "memory");
    short8 af[4], bw[4];
    #pragma unroll
    for (int i = 0; i < 4; i++) af[i] = *(const short8*)(rAb + cur + i * 256);
    #pragma unroll
    for (int j = 0; j < 4; j++) bw[j] = *(const short8*)(rBb + cur + j * 256);
    #pragma unroll
    for (int i = 0; i < 4; i++)
      #pragma unroll
      for (int j = 0; j < 4; j++)
        acc[i][j] = __builtin_amdgcn_mfma_f32_16x16x32_bf16(af[i], bw[j], acc[i][j], 0, 0, 0);
    asm volatile("" ::: "memory");
    __builtin_amdgcn_s_barrier();   // all reads of buf cur done -> safe to overwrite next iter
  }
}

#define EPI_BASES(m0, n0)                                      \
  int lane = threadIdx.x & 63, wv = threadIdx.x >> 6;          \
  int crow_base = (m0) + (wv >> 1) * 64 + (lane >> 4) * 4;     \
  int ccol_base = (n0) + (wv & 1) * 64 + (lane & 15);

__global__ __launch_bounds__(256) void gemm_up_kernel(const bf16* __restrict__ A,
    const bf16* __restrict__ W, bf16* __restrict__ C, int N, int K) {
  __shared__ bf16 Als[8192], Bls[8192];
  f32x4 acc[4][4];
  int m0, n0;
  remap_grid(m0, n0);
  gemm128_core(A, W, K, Als, Bls, acc, m0, n0);
  EPI_BASES(m0, n0)
  #pragma unroll
  for (int i = 0; i < 4; i++)
    #pragma unroll
    for (int j = 0; j < 4; j++) {
      int col = ccol_base + j * 16;
      #pragma unroll
      for (int r = 0; r < 4; r++)
        C[(size_t)(crow_base + i * 16 + r) * N + col] = __float2bfloat16(acc[i][j][r]);
    }
}

__global__ __launch_bounds__(256) void gemm_sf_kernel(const bf16* __restrict__ A,
    const bf16* __restrict__ W, const float* __restrict__ bias,
    bf16* __restrict__ skipb, float* __restrict__ icapT, float* __restrict__ fcapT,
    bf16* __restrict__ oqkv) {
  __shared__ bf16 Als[8192], Bls[8192];
  f32x4 acc[4][4];
  int m0, n0;
  remap_grid(m0, n0);
  gemm128_core(A, W, 1536, Als, Bls, acc, m0, n0);
  EPI_BASES(m0, n0)
  #pragma unroll
  for (int i = 0; i < 4; i++)
    #pragma unroll
    for (int j = 0; j < 4; j++) {
      int col = ccol_base + j * 16;
      float bv = bias[col];
      #pragma unroll
      for (int r = 0; r < 4; r++) {
        int row = crow_base + i * 16 + r;
        float v = acc[i][j][r] + bv;
        if (col < 768) {
          skipb[(size_t)row * 768 + col] = __float2bfloat16(v);
        } else if (col < 832) {
          if (col < 784) {       // fused gate_cap: capped gates, [bh][t] layout
            int g = col - 768;
            float cap = CAPV * tanhf(v * (1.f / CAPV));
            int b = row >> 10, t = row & 1023;
            int idx = (((b << 3) | (g & 7)) << 10) | t;
            if (g < 8) icapT[idx] = cap; else fcapT[idx] = cap;
          }
        } else if (col < 3904) {
          oqkv[(size_t)row * OQKV_W + (col - 832)] = __float2bfloat16(v);
        }
      }
    }
}

__global__ __launch_bounds__(256) void gemm_down_kernel(const bf16* __restrict__ A,
    const bf16* __restrict__ W, const bf16* __restrict__ skipb, const bf16* __restrict__ srt,
    const float* __restrict__ x, float* __restrict__ ys) {
  __shared__ bf16 Als[8192], Bls[8192];
  f32x4 acc[4][4];
  int m0, n0;
  remap_grid(m0, n0);
  gemm128_core(A, W, 768, Als, Bls, acc, m0, n0);
  EPI_BASES(m0, n0)
  #pragma unroll
  for (int i = 0; i < 4; i++)
    #pragma unroll
    for (int j = 0; j < 4; j++) {
      int col = ccol_base + j * 16;
      #pragma unroll
      for (int r = 0; r < 4; r++) {
        size_t idx = (size_t)(crow_base + i * 16 + r) * 768 + col;
        ys[idx] = (acc[i][j][r] + cvt(skipb[idx])) * cvt(srt[idx]) + x[idx];
      }
    }
}

// ---------------- causal feature conv + silu; silu(rt) ----------------
__global__ __launch_bounds__(256) void conv_silu_kernel(const bf16* __restrict__ up,
    const float* __restrict__ cw, bf16* __restrict__ xc, bf16* __restrict__ srt) {
  int row = blockIdx.x;
  const bf16* xr = up + (size_t)row * NPAD_UP;
  float w0 = cw[0], w1 = cw[1], w2 = cw[2], w3 = cw[3];
  int t = threadIdx.x;
  #pragma unroll
  for (int u = 0; u < 6; ++u) {
    int j = t + u * 256;
    float xm3 = j >= 3 ? cvt(xr[j - 3]) : 0.f;
    float xm2 = j >= 2 ? cvt(xr[j - 2]) : 0.f;
    float xm1 = j >= 1 ? cvt(xr[j - 1]) : 0.f;
    float x0  = cvt(xr[j]);
    float c = w0 * xm3 + w1 * xm2 + w2 * xm1 + w3 * x0;
    xc[(size_t)row * 1536 + j] = __float2bfloat16(c / (1.f + expf(-c)));
  }
  #pragma unroll
  for (int u = 0; u < 3; ++u) {
    int j = t + u * 256;
    float r = cvt(xr[1536 + j]);
    srt[(size_t)row * 768 + j] = __float2bfloat16(r / (1.f + expf(-r)));
  }
}

// ---------------- B0b: sequential m-scan + per-chunk A cumsum (lane = bh) ----------------
__global__ __launch_bounds__(64) void mscan_kernel(const float* __restrict__ icapT,
    const float* __restrict__ fcapT, float* __restrict__ mbuf, float* __restrict__ Abuf,
    float* __restrict__ mf) {
  int bh = threadIdx.x;
  int base = bh * 1024;
  float m = 0.f, A = 0.f;
  for (int t0 = 0; t0 < 1024; t0 += 4) {
    f32x4 fc = *reinterpret_cast<const f32x4*>(fcapT + base + t0);
    f32x4 ic = *reinterpret_cast<const f32x4*>(icapT + base + t0);
    f32x4 mo, Ao;
    #pragma unroll
    for (int u = 0; u < 4; ++u) {
      A = (((t0 + u) & (CH - 1)) == 0) ? fc[u] : A + fc[u];
      m = fmaxf(fc[u] + m, ic[u]);
      mo[u] = m; Ao[u] = A;
    }
    *reinterpret_cast<f32x4*>(mbuf + base + t0) = mo;
    *reinterpret_cast<f32x4*>(Abuf + base + t0) = Ao;
  }
  mf[bh] = m;
}

// ---------------- B1: per-(bh,chunk) intra-chunk attention + chunk summary ----------------
__global__ __launch_bounds__(256) void chunk_kernel(
    const bf16* __restrict__ oqkv, const float* __restrict__ icapT,
    const float* __restrict__ mbuf, const float* __restrict__ Abuf,
    bf16* __restrict__ hbuf, bf16* __restrict__ UC, float* __restrict__ nUn,
    float* __restrict__ denp) {
  int bh = blockIdx.x, c = blockIdx.y;
  int b = bh >> 3, h = bh & 7;
  int tid = threadIdx.x, lane = tid & 63, wv = tid >> 6;
  int mh = wv >> 1, nh = wv & 1;
  int rsel = lane & 15, koff = (lane >> 4) * 8;
  int crow = (lane >> 4) * 4, ccol = lane & 15;
  __shared__ float At[CH], mt[CH], colt[CH], wsh[CH], rsw[2][CH];
  __shared__ bf16 P[CH][72];
  __shared__ bf16 Vt[96][72];
  __shared__ bf16 Kw[96][72];
  int t0g = c * CH;
  size_t grow0 = (size_t)(b * 1024 + t0g);
  const int qcol = 768 + h * 96, kcol = 1536 + h * 96, vcol = 2304 + h * 96;
  if (tid < CH) {
    float a  = Abuf[bh * 1024 + t0g + tid];
    float mm = mbuf[bh * 1024 + t0g + tid];
    float ic = icapT[bh * 1024 + t0g + tid];
    At[tid] = a; mt[tid] = mm; colt[tid] = ic - a;
  }
  __syncthreads();
  if (tid < CH) wsh[tid] = INV_SQRT_D * expf((At[CH - 1] - mt[CH - 1]) + colt[tid]);
  __syncthreads();
  #pragma unroll
  for (int it = 0; it < (CH * 96) / 256; ++it) {
    int idx = tid + it * 256;
    int s = idx / 96, e = idx - s * 96;
    const bf16* rp = oqkv + (grow0 + s) * OQKV_W;
    Vt[e][s] = rp[vcol + e];
    Kw[e][s] = __float2bfloat16(wsh[s] * cvt(rp[kcol + e]));
  }
  // S = Q K^T : wave -> 32x32 tile
  {
    const bf16* aptr = oqkv + (grow0 + mh * 32 + rsel) * OQKV_W + qcol + koff;
    const bf16* wptr = oqkv + (grow0 + nh * 32 + rsel) * OQKV_W + kcol + koff;
    f32x4 sacc[2][2];
    #pragma unroll
    for (int i = 0; i < 2; i++)
      #pragma unroll
      for (int j = 0; j < 2; j++) sacc[i][j] = (f32x4){0.f, 0.f, 0.f, 0.f};
    for (int k0 = 0; k0 < 96; k0 += 32) {
      short8 af[2], bfr[2];
      #pragma unroll
      for (int i = 0; i < 2; i++)
        af[i] = *reinterpret_cast<const short8*>(aptr + (size_t)i * 16 * OQKV_W + k0);
      #pragma unroll
      for (int j = 0; j < 2; j++)
        bfr[j] = *reinterpret_cast<const short8*>(wptr + (size_t)j * 16 * OQKV_W + k0);
      #pragma unroll
      for (int i = 0; i < 2; i++)
        #pragma unroll
        for (int j = 0; j < 2; j++)
          sacc[i][j] = __builtin_amdgcn_mfma_f32_16x16x32_bf16(af[i], bfr[j], sacc[i][j], 0, 0, 0);
    }
    float rsum[2][4] = {};
    #pragma unroll
    for (int i = 0; i < 2; i++)
      #pragma unroll
      for (int j = 0; j < 2; j++) {
        int col = nh * 32 + ccol + j * 16;
        #pragma unroll
        for (int r = 0; r < 4; r++) {
          int row = mh * 32 + crow + i * 16 + r;
          float v = 0.f;
          if (col <= row)
            v = sacc[i][j][r] * (INV_SQRT_D * expf((At[row] - mt[row]) + colt[col]));
          P[row][col] = __float2bfloat16(v);
          rsum[i][r] += v;
        }
      }
    #pragma unroll
    for (int msk = 1; msk < 16; msk <<= 1)
      #pragma unroll
      for (int i = 0; i < 2; i++)
        #pragma unroll
        for (int r = 0; r < 4; r++) rsum[i][r] += __shfl_xor(rsum[i][r], msk);
    if (ccol == 0)
      #pragma unroll
      for (int i = 0; i < 2; i++)
        #pragma unroll
        for (int r = 0; r < 4; r++) rsw[nh][mh * 32 + crow + i * 16 + r] = rsum[i][r];
  }
  __syncthreads();
  if (tid < CH) denp[bh * 1024 + t0g + tid] = rsw[0][tid] + rsw[1][tid];
  // PV
  {
    f32x4 pacc[2][3];
    #pragma unroll
    for (int i = 0; i < 2; i++)
      #pragma unroll
      for (int j = 0; j < 3; j++) pacc[i][j] = (f32x4){0.f, 0.f, 0.f, 0.f};
    const bf16* pp = &P[mh * 32 + rsel][0];
    for (int k0 = 0; k0 < CH; k0 += 32) {
      short8 af[2], bfr[3];
      #pragma unroll
      for (int i = 0; i < 2; i++)
        af[i] = *reinterpret_cast<const short8*>(pp + (size_t)i * 16 * 72 + koff + k0);
      #pragma unroll
      for (int j = 0; j < 3; j++)
        bfr[j] = *reinterpret_cast<const short8*>(&Vt[nh * 48 + j * 16 + rsel][0] + koff + k0);
      #pragma unroll
      for (int i = 0; i < 2; i++)
        #pragma unroll
        for (int j = 0; j < 3; j++)
          pacc[i][j] = __builtin_amdgcn_mfma_f32_16x16x32_bf16(af[i], bfr[j], pacc[i][j], 0, 0, 0);
    }
    #pragma unroll
    for (int i = 0; i < 2; i++)
      #pragma unroll
      for (int j = 0; j < 3; j++) {
        int col = nh * 48 + ccol + j * 16;
        #pragma unroll
        for (int r = 0; r < 4; r++) {
          int row = mh * 32 + crow + i * 16 + r;
          hbuf[(grow0 + row) * 768 + h * 96 + col] = __float2bfloat16(pacc[i][j][r]);
        }
      }
  }
  // U = V^T diag(w) K
  {
    f32x4 uacc[3][3];
    #pragma unroll
    for (int i = 0; i < 3; i++)
      #pragma unroll
      for (int j = 0; j < 3; j++) uacc[i][j] = (f32x4){0.f, 0.f, 0.f, 0.f};
    for (int k0 = 0; k0 < CH; k0 += 32) {
      short8 af[3], bfr[3];
      #pragma unroll
      for (int i = 0; i < 3; i++)
        af[i] = *reinterpret_cast<const short8*>(&Vt[mh * 48 + i * 16 + rsel][0] + koff + k0);
      #pragma unroll
      for (int j = 0; j < 3; j++)
        bfr[j] = *reinterpret_cast<const short8*>(&Kw[nh * 48 + j * 16 + rsel][0] + koff + k0);
      #pragma unroll
      for (int i = 0; i < 3; i++)
        #pragma unroll
        for (int j = 0; j < 3; j++)
          uacc[i][j] = __builtin_amdgcn_mfma_f32_16x16x32_bf16(af[i], bfr[j], uacc[i][j], 0, 0, 0);
    }
    size_t ub = ((size_t)c * 64 + bh) * 9216;
    #pragma unroll
    for (int i = 0; i < 3; i++)
      #pragma unroll
      for (int j = 0; j < 3; j++) {
        int e = nh * 48 + ccol + j * 16;
        #pragma unroll
        for (int r = 0; r < 4; r++) {
          int d = mh * 48 + crow + i * 16 + r;
          UC[ub + (size_t)d * 96 + e] = __float2bfloat16(uacc[i][j][r]);
        }
      }
  }
  if (tid < 96) {
    float s = 0.f;
    #pragma unroll 16
    for (int s2 = 0; s2 < CH; ++s2) s += cvt(Kw[tid][s2]);
    nUn[((size_t)c * 64 + bh) * 96 + tid] = s;
  }
}

// ---------------- B2: chunk-boundary C recurrence (in-place U -> Cstart) ----------------
__global__ __launch_bounds__(256) void cscan_kernel(bf16* __restrict__ UC,
    const float* __restrict__ mbuf, const float* __restrict__ Abuf, float* __restrict__ Cf) {
  int bh = blockIdx.y;
  int elem = blockIdx.x * 256 + threadIdx.x;
  if (elem >= 9216) return;
  float cur = 0.f;
  for (int c = 0; c < NCH; ++c) {
    size_t o = ((size_t)c * 64 + bh) * 9216 + elem;
    float u = cvt(UC[o]);
    UC[o] = __float2bfloat16(cur);
    float mprev = c ? mbuf[bh * 1024 + c * CH - 1] : 0.f;
    float mend  = mbuf[bh * 1024 + c * CH + CH - 1];
    float aend  = Abuf[bh * 1024 + c * CH + CH - 1];
    cur = expf(aend + mprev - mend) * cur + u;
  }
  Cf[(size_t)bh * 9216 + elem] = cur;
}

__global__ __launch_bounds__(128) void nscan_kernel(float* __restrict__ nUn,
    const float* __restrict__ mbuf, const float* __restrict__ Abuf, float* __restrict__ nf) {
  int bh = blockIdx.x, e = threadIdx.x;
  if (e >= 96) return;
  float cur = 1.f;
  for (int c = 0; c < NCH; ++c) {
    size_t o = ((size_t)c * 64 + bh) * 96 + e;
    float u = nUn[o];
    nUn[o] = cur;
    float mprev = c ? mbuf[bh * 1024 + c * CH - 1] : 0.f;
    float mend  = mbuf[bh * 1024 + c * CH + CH - 1];
    float aend  = Abuf[bh * 1024 + c * CH + CH - 1];
    cur = expf(aend + mprev - mend) * cur + u;
  }
  nf[bh * 96 + e] = cur;
}

// ---------------- B3: add carry terms, o-gate, finalize h ----------------
__global__ __launch_bounds__(256) void carry_kernel(
    const bf16* __restrict__ oqkv, const bf16* __restrict__ Cst, const float* __restrict__ nstg,
    const float* __restrict__ mbuf, const float* __restrict__ Abuf,
    const float* __restrict__ denp, bf16* __restrict__ hbuf) {
  int bh = blockIdx.x, c = blockIdx.y;
  int b = bh >> 3, h = bh & 7;
  int tid = threadIdx.x, lane = tid & 63, wv = tid >> 6;
  int mh = wv >> 1, nh = wv & 1;
  int rsel = lane & 15, koff = (lane >> 4) * 8;
  int crow = (lane >> 4) * 4, ccol = lane & 15;
  __shared__ float carry[CH], den[CH], nsh[96];
  __shared__ bf16 osd[CH][104], hp[CH][104];
  int t0g = c * CH;
  size_t grow0 = (size_t)(b * 1024 + t0g);
  float mprev = c ? mbuf[bh * 1024 + t0g - 1] : 0.f;
  if (tid < 96) nsh[tid] = nstg[((size_t)c * 64 + bh) * 96 + tid];
  if (tid < CH)
    carry[tid] = expf(Abuf[bh * 1024 + t0g + tid] + mprev - mbuf[bh * 1024 + t0g + tid]);
  #pragma unroll
  for (int it = 0; it < (CH * 96) / 256; ++it) {
    int idx = tid + it * 256;
    int s = idx / 96, e = idx - s * 96;
    osd[s][e] = oqkv[(grow0 + s) * OQKV_W + h * 96 + e];
    hp[s][e]  = hbuf[(grow0 + s) * 768 + h * 96 + e];
  }
  __syncthreads();
  if (tid < CH) {
    const bf16* qr = oqkv + (grow0 + tid) * OQKV_W + 768 + h * 96;
    float qn = 0.f;
    #pragma unroll 16
    for (int e = 0; e < 96; ++e) qn += cvt(qr[e]) * nsh[e];
    den[tid] = fmaxf(denp[bh * 1024 + t0g + tid] + carry[tid] * qn, 1.f);
  }
  size_t cb = ((size_t)c * 64 + bh) * 9216;
  const bf16* aptr = oqkv + (grow0 + mh * 32 + rsel) * OQKV_W + 768 + h * 96 + koff;
  f32x4 qa[2][3];
  #pragma unroll
  for (int i = 0; i < 2; i++)
    #pragma unroll
    for (int j = 0; j < 3; j++) qa[i][j] = (f32x4){0.f, 0.f, 0.f, 0.f};
  for (int k0 = 0; k0 < 96; k0 += 32) {
    short8 af[2], bfr[3];
    #pragma unroll
    for (int i = 0; i < 2; i++)
      af[i] = *reinterpret_cast<const short8*>(aptr + (size_t)i * 16 * OQKV_W + k0);
    #pragma unroll
    for (int j = 0; j < 3; j++)
      bfr[j] = *reinterpret_cast<const short8*>(Cst + cb + (size_t)(nh * 48 + j * 16 + rsel) * 96 + koff + k0);
    #pragma unroll
    for (int i = 0; i < 2; i++)
      #pragma unroll
      for (int j = 0; j < 3; j++)
        qa[i][j] = __builtin_amdgcn_mfma_f32_16x16x32_bf16(af[i], bfr[j], qa[i][j], 0, 0, 0);
  }
  __syncthreads();
  #pragma unroll
  for (int i = 0; i < 2; i++)
    #pragma unroll
    for (int j = 0; j < 3; j++) {
      int col = nh * 48 + ccol + j * 16;
      #pragma unroll
      for (int r = 0; r < 4; r++) {
        int row = mh * 32 + crow + i * 16 + r;
        float oc = CAPV * tanhf(cvt(osd[row][col]) * (1.f / CAPV));
        float og = 1.f / (1.f + expf(-oc));
        float hv = og * (cvt(hp[row][col]) + carry[row] * qa[i][j][r]) / den[row];
        hbuf[(grow0 + row) * 768 + h * 96 + col] = __float2bfloat16(hv);
      }
    }
}

extern "C" void kernel_launch(void* const* d_in, const int* in_sizes, int n_in,
                              void* d_out, int out_size, void* d_ws, size_t ws_size,
                              hipStream_t stream) {
  const float* x       = (const float*)d_in[0];
  const float* ln1_g   = (const float*)d_in[1];
  const float* ln1_b   = (const float*)d_in[2];
  const float* W_up_l  = (const float*)d_in[3];
  const float* W_up_r  = (const float*)d_in[4];
  const float* conv_w  = (const float*)d_in[5];
  const float* W_skip  = (const float*)d_in[6];
  const float* fused_W = (const float*)d_in[7];
  const float* fused_b = (const float*)d_in[8];
  const float* ln2_g   = (const float*)d_in[9];
  const float* ln2_b   = (const float*)d_in[10];
  const float* W_down  = (const float*)d_in[11];

  char* ws = (char*)d_ws;
  size_t off = 0;
  auto carve = [&](size_t bytes) -> char* {
    char* p = ws + off;
    off += (bytes + 255) & ~(size_t)255;
    return p;
  };
  bf16* wup    = (bf16*)carve((size_t)NPAD_UP * 768 * 2);
  bf16* wsf2   = (bf16*)carve((size_t)SFW3 * 1536 * 2);
  bf16* wdn    = (bf16*)carve((size_t)768 * 768 * 2);
  float* bias2 = (float*)carve(SFW3 * 4);
  bf16* srt    = (bf16*)carve((size_t)NTOK * 768 * 2);
  bf16* skipb  = (bf16*)carve((size_t)NTOK * 768 * 2);
  float* icapT = (float*)carve((size_t)65536 * 4);   // NOT aliased with xc (gemm_sf writes these while reading xc)
  float* fcapT = (float*)carve((size_t)65536 * 4);
  bf16* oqkv   = (bf16*)carve((size_t)NTOK * OQKV_W * 2);
  char* xcr    = carve((size_t)NTOK * 1536 * 2);          // 25.2 MB multi-use
  char* R      = carve((size_t)NTOK * 768 * 2 + (size_t)NTOK * NPAD_UP * 2);
  bf16* xn     = (bf16*)R;
  bf16* up_out = (bf16*)(R + (size_t)NTOK * 768 * 2);
  bf16* hbuf   = (bf16*)R;
  bf16* hn     = (bf16*)(R + (size_t)NTOK * 768 * 2);

  bf16* xc = (bf16*)xcr;
  size_t o2 = 0;
  auto carve2 = [&](size_t bytes) -> char* {
    char* p = xcr + o2;
    o2 += (bytes + 255) & ~(size_t)255;
    return p;
  };
  float* mbuf  = (float*)carve2((size_t)65536 * 4);
  float* Abuf  = (float*)carve2((size_t)65536 * 4);
  float* denp  = (float*)carve2((size_t)65536 * 4);
  bf16*  UC    = (bf16*)carve2((size_t)NCH * 64 * 9216 * 2);
  float* nUn   = (float*)carve2((size_t)NCH * 64 * 96 * 4);

  auto blocks = [](long n) { return (unsigned)((n + 255) / 256); };

  long n1 = 1536L * 768, n2 = 768L * 768;
  cast_pad_kernel<<<blocks(n1), 256, 0, stream>>>(W_up_l, wup, n1);
  cast_pad_kernel<<<blocks(n2), 256, 0, stream>>>(W_up_r, wup + n1, n2);
  build_wsf2_kernel<<<dim3(6, SFW3), 256, 0, stream>>>(W_skip, fused_W, wsf2);
  cast_pad_kernel<<<blocks(n2), 256, 0, stream>>>(W_down, wdn, n2);
  build_bias2_kernel<<<blocks(SFW3), 256, 0, stream>>>(fused_b, bias2);

  float* out_f = (float*)d_out;
  float* Cf_out = out_f + YS_ELEMS;
  float* nf_out = Cf_out + (size_t)64 * 9216;
  float* mf_out = nf_out + 64 * 96;

  // phase A
  ln_kernel<float><<<NTOK, 256, 0, stream>>>(x, ln1_g, ln1_b, xn);
  gemm_up_kernel<<<dim3(NPAD_UP / 128, NTOK / 128), 256, 0, stream>>>(
      xn, wup, up_out, NPAD_UP, 768);
  conv_silu_kernel<<<NTOK, 256, 0, stream>>>(up_out, conv_w, xc, srt);
  gemm_sf_kernel<<<dim3(SFW3 / 128, NTOK / 128), 256, 0, stream>>>(
      xc, wsf2, bias2, skipb, icapT, fcapT, oqkv);

  // phase B: chunked parallel mLSTM
  mscan_kernel<<<1, 64, 0, stream>>>(icapT, fcapT, mbuf, Abuf, mf_out);
  chunk_kernel<<<dim3(64, NCH), 256, 0, stream>>>(
      oqkv, icapT, mbuf, Abuf, hbuf, UC, nUn, denp);
  cscan_kernel<<<dim3(36, 64), 256, 0, stream>>>(UC, mbuf, Abuf, Cf_out);
  nscan_kernel<<<64, 128, 0, stream>>>(nUn, mbuf, Abuf, nf_out);
  carry_kernel<<<dim3(64, NCH), 256, 0, stream>>>(
      oqkv, UC, nUn, mbuf, Abuf, denp, hbuf);

  // phase C
  ln_kernel<bf16><<<NTOK, 256, 0, stream>>>(hbuf, ln2_g, ln2_b, hn);
  gemm_down_kernel<<<dim3(768 / 128, NTOK / 128), 256, 0, stream>>>(
      hn, wdn, skipb, srt, x, out_f);
}